// Round 2
// baseline (743.152 us; speedup 1.0000x reference)
//
#include <hip/hip_runtime.h>

typedef unsigned short u16;

// Problem constants: B=8, N=256, F=64, C=16, K=2
#define EPSV 1e-4f

// Output element offsets (element counts, dtype-agnostic):
//   h_out  [0, 131072)   coord_out [131072, 229376)   category [229376, 1277952)
// The category region (>=2MB in bytes) is used as scratch for HA/HBT (bf16)
// until k_copycat overwrites it at the end.

// ---------------- ws layout (fp32 elements), total ~1.55 MB ----------------
static constexpr int WS_FLAG = 0;                      // int flag: 1=bf16 inputs, 0=fp32
static constexpr int WS_ATT  = 16;                     // [2048][16] relu(W_qm h + b_qm)
static constexpr int WS_CT   = WS_ATT + 2048 * 16;     // [8][48][256] coord transposed fp32
static constexpr int WS_AGG  = WS_CT  + 8 * 48 * 256;  // [2048][64] sum_j edge_feat (j!=i)
static constexpr int WS_CAC  = WS_AGG + 2048 * 64;     // [2048][48] sum_j factors*(ci-cj)
static constexpr int WS_WHAT = WS_CAC + 2048 * 48;     // [64][192] W cols 0:64 (h_i part) [k][o]
static constexpr int WS_WHBT = WS_WHAT + 64 * 192;     // [64][192] W cols 64:128 (h_j part)
static constexpr int WS_WDT  = WS_WHBT + 64 * 192;     // [3][16][64] W cols 128:144 (dist part)
static constexpr int WS_WE2T = WS_WDT  + 3 * 16 * 64;  // [64][64]  W_e2^T  [o][f]
static constexpr int WS_WC2T = WS_WE2T + 64 * 64;      // [2][64][16] W_cat2^T [m][o][c]
static constexpr int WS_WF1T = WS_WC2T + 2 * 64 * 16;  // [16][16] W_f1^T [c][c2]
static constexpr int WS_WF2T = WS_WF1T + 256;          // [16][16]
static constexpr int WS_WN1T = WS_WF2T + 256;          // [128][64] W_n1^T [k][f]
static constexpr int WS_WN2T = WS_WN1T + 128 * 64;     // [64][64]  W_n2^T [o][f]
static constexpr int WS_BE2  = WS_WN2T + 64 * 64;      // [64]
static constexpr int WS_BC2  = WS_BE2 + 64;            // [32]
static constexpr int WS_BF1  = WS_BC2 + 32;            // [16]
static constexpr int WS_BF2  = WS_BF1 + 16;            // [16]
static constexpr int WS_BN1  = WS_BF2 + 16;            // [64]
static constexpr int WS_BN2  = WS_BN1 + 64;            // [64]

static __device__ __forceinline__ float bfld(u16 v) {
  return __uint_as_float(((unsigned)v) << 16);
}
static __device__ __forceinline__ u16 f2b(float x) {  // round-to-nearest-even
  unsigned u = __float_as_uint(x);
  u += 0x7FFFu + ((u >> 16) & 1u);
  return (u16)(u >> 16);
}
// dtype-flexible input load: flag=1 -> bf16, flag=0 -> fp32
static __device__ __forceinline__ float ldv(const void* p, int i, int flag) {
  return flag ? bfld(((const u16*)p)[i]) : ((const float*)p)[i];
}
// dtype-flexible output store (element index; element size per flag)
static __device__ __forceinline__ void stv(void* p, int i, float v, int flag) {
  if (flag) ((u16*)p)[i] = f2b(v);
  else      ((float*)p)[i] = v;
}
static __device__ __forceinline__ u16* scratchHA(void* outv, int flag) {
  return (u16*)((char*)outv + (size_t)229376 * (flag ? 2 : 4));
}

// ---------------- K00: dtype sniff + weight transposes (1 block) ------------
__global__ void k_prep_w(const void* __restrict__ h,
                         const void* __restrict__ We1, const void* __restrict__ Wc1,
                         const void* __restrict__ We2, const void* __restrict__ be2,
                         const void* __restrict__ Wc2, const void* __restrict__ bc2,
                         const void* __restrict__ Wf1, const void* __restrict__ bf1,
                         const void* __restrict__ Wf2, const void* __restrict__ bf2,
                         const void* __restrict__ Wn1, const void* __restrict__ bn1,
                         const void* __restrict__ Wn2, const void* __restrict__ bn2,
                         float* __restrict__ ws) {
  const int t = threadIdx.x;  // 256 threads
  __shared__ int sflag;
  if (t == 0) {
    // sniff: bf16 N(0,1) data -> nearly all u16 words have sane exponent field;
    // fp32 data misread as u16 -> even words are mantissa garbage (~60% pass).
    const u16* hu = (const u16*)h;
    int cnt = 0;
    for (int i = 0; i < 128; ++i) {
      unsigned e = (hu[i] >> 7) & 0xFFu;
      if (e >= 100u && e <= 150u) ++cnt;
      else if (hu[i] == 0) ++cnt;
    }
    sflag = (cnt >= 112) ? 1 : 0;
    ((int*)ws)[WS_FLAG] = sflag;
  }
  __syncthreads();
  const int flag = sflag;

  // stacked layer-1 weights: rows o<64 -> W_e1[o], rows 64..191 -> W_cat1[(o-64)]
  for (int idx = t; idx < 64 * 192; idx += 256) {
    int k = idx / 192, o = idx % 192;
    const int rowbase = (o < 64) ? 0 : 1;
    const void* src = rowbase ? Wc1 : We1;
    const int roff = (rowbase ? (o - 64) : o) * 144;
    ws[WS_WHAT + idx] = ldv(src, roff + k, flag);
    ws[WS_WHBT + idx] = ldv(src, roff + 64 + k, flag);
  }
  for (int idx = t; idx < 3 * 16 * 64; idx += 256) {  // [m][c][o], cols 128:144
    int m = idx / 1024, c = (idx >> 6) & 15, o = idx & 63;
    const void* src = (m == 0) ? We1 : Wc1;
    const int roff = ((m == 0) ? o : ((m - 1) * 64 + o)) * 144;
    ws[WS_WDT + idx] = ldv(src, roff + 128 + c, flag);
  }
  for (int idx = t; idx < 64 * 64; idx += 256) {      // We2T[o][f] = We2[f][o]
    int o = idx >> 6, f = idx & 63;
    ws[WS_WE2T + idx] = ldv(We2, f * 64 + o, flag);
  }
  for (int idx = t; idx < 2 * 64 * 16; idx += 256) {  // Wc2T[m][o][c] = Wc2[m][c][o]
    int m = idx / 1024, o = (idx >> 4) & 63, c = idx & 15;
    ws[WS_WC2T + idx] = ldv(Wc2, (m * 16 + c) * 64 + o, flag);
  }
  {
    int c = t >> 4, c2 = t & 15;  // Wf1T[c][c2] = Wf1[c2][c]
    ws[WS_WF1T + t] = ldv(Wf1, c2 * 16 + c, flag);
    ws[WS_WF2T + t] = ldv(Wf2, c2 * 16 + c, flag);
  }
  for (int idx = t; idx < 128 * 64; idx += 256) {     // Wn1T[k][f] = Wn1[f][k]
    int k = idx >> 6, f = idx & 63;
    ws[WS_WN1T + idx] = ldv(Wn1, f * 128 + k, flag);
  }
  for (int idx = t; idx < 64 * 64; idx += 256) {      // Wn2T[o][f] = Wn2[f][o]
    int o = idx >> 6, f = idx & 63;
    ws[WS_WN2T + idx] = ldv(Wn2, f * 64 + o, flag);
  }
  if (t < 64) ws[WS_BE2 + t] = ldv(be2, t, flag);
  if (t < 32) ws[WS_BC2 + t] = ldv(bc2, t, flag);
  if (t < 16) { ws[WS_BF1 + t] = ldv(bf1, t, flag); ws[WS_BF2 + t] = ldv(bf2, t, flag); }
  if (t >= 64 && t < 128)  ws[WS_BN1 + t - 64]  = ldv(bn1, t - 64, flag);
  if (t >= 128 && t < 192) ws[WS_BN2 + t - 128] = ldv(bn2, t - 128, flag);
}

// ---------------- K0: per-node precompute (2048 blocks x 64) ----------------
__global__ void k_prep_node(const void* __restrict__ h, const void* __restrict__ coord,
                            const void* __restrict__ be1, const void* __restrict__ bc1,
                            const void* __restrict__ Wqm, const void* __restrict__ bqm,
                            float* __restrict__ ws, void* __restrict__ outv) {
  const int node = blockIdx.x;            // b*256 + n
  const int b = node >> 8, n = node & 255;
  const int lane = threadIdx.x;           // 64
  const int flag = ((const int*)ws)[WS_FLAG];
  u16* HA16  = scratchHA(outv, flag);                 // [2048][192]
  u16* HBT16 = HA16 + 2048 * 192;                     // [8][192][256]
  __shared__ float hF[64];
  hF[lane] = ldv(h, node * 64 + lane, flag);
  __syncthreads();
  const float* __restrict__ WhaT = ws + WS_WHAT;
  const float* __restrict__ WhbT = ws + WS_WHBT;
#pragma unroll
  for (int r = 0; r < 3; ++r) {
    const int o = r * 64 + lane;
    float sa = (o < 64) ? ldv(be1, o, flag) : ldv(bc1, o - 64, flag);  // fold bias
    float sb = 0.f;
    for (int k = 0; k < 64; ++k) {
      float hk = hF[k];
      sa += WhaT[k * 192 + o] * hk;
      sb += WhbT[k * 192 + o] * hk;
    }
    HA16[node * 192 + o] = f2b(sa);
    HBT16[(b * 192 + o) * 256 + n] = f2b(sb);
  }
  if (lane < 16) {  // att = relu(W_qm h + b_qm)
    float s = ldv(bqm, lane, flag);
    for (int f = 0; f < 64; ++f) s += ldv(Wqm, lane * 64 + f, flag) * hF[f];
    ws[WS_ATT + node * 16 + lane] = fmaxf(s, 0.f);
  }
  if (lane < 48) {  // coord transposed to [b][cd][n] fp32
    ws[WS_CT + (b * 48 + lane) * 256 + n] = ldv(coord, node * 48 + lane, flag);
  }
}

// ---------------- K1: edge kernel (2048 blocks x 256) -----------------------
__global__ __launch_bounds__(256) void k_edge(const void* __restrict__ cat,
                                              float* __restrict__ ws,
                                              void* __restrict__ outv) {
  const int node = blockIdx.x;
  const int b = node >> 8, i = node & 255;
  const int tid = threadIdx.x;
  const int j = tid;
  const int wave = tid >> 6, lane = tid & 63;
  const int flag = ((const int*)ws)[WS_FLAG];
  const u16* HA16  = scratchHA(outv, flag);
  const u16* HBT16 = HA16 + 2048 * 192;

  __shared__ float distT[16 * 256];   // 16 KB
  __shared__ u16   h1T[64 * 256];     // 32 KB
  __shared__ float red[4 * 64];       // 1 KB

  const u16* __restrict__ HaR  = HA16 + node * 192;
  const u16* __restrict__ HbB  = HBT16 + b * 192 * 256;
  const float* __restrict__ cTb  = ws + WS_CT + b * 48 * 256;
  const float* __restrict__ WdT  = ws + WS_WDT;
  const float* __restrict__ We2T = ws + WS_WE2T;
  const float* __restrict__ Wc2T = ws + WS_WC2T;
  const float* __restrict__ Wf1T = ws + WS_WF1T;
  const float* __restrict__ Wf2T = ws + WS_WF2T;
  float* __restrict__ aggO  = ws + WS_AGG;
  float* __restrict__ caccO = ws + WS_CAC;

  // ---- pairwise channel distances ----
#pragma unroll
  for (int c = 0; c < 16; ++c) {
    float s = 0.f;
#pragma unroll
    for (int d = 0; d < 3; ++d) {
      const int cd = c * 3 + d;
      float ci = cTb[cd * 256 + i];   // uniform
      float cj = cTb[cd * 256 + j];   // coalesced
      float df = ci - cj;
      s += df * df;
    }
    distT[c * 256 + tid] = sqrtf(s);
  }

  // ---- edge MLP layer 1: acc = Ha + Hb + Wd*dist ----
  float acc[64];
#pragma unroll
  for (int o = 0; o < 64; ++o) acc[o] = bfld(HaR[o]) + bfld(HbB[o * 256 + j]);
  for (int c = 0; c < 16; ++c) {
    float dc = distT[c * 256 + tid];
    const float* w = WdT + c * 64;
#pragma unroll
    for (int o = 0; o < 64; ++o) acc[o] += w[o] * dc;
  }
#pragma unroll
  for (int o = 0; o < 64; ++o) h1T[o * 256 + tid] = f2b(fmaxf(acc[o], 0.f));

  // ---- edge MLP layer 2 ----
  float ef[64];
#pragma unroll
  for (int f = 0; f < 64; ++f) ef[f] = ws[WS_BE2 + f];
#pragma unroll 2
  for (int o = 0; o < 64; ++o) {
    float a = bfld(h1T[o * 256 + tid]);
    const float* w = We2T + o * 64;
#pragma unroll
    for (int f = 0; f < 64; ++f) ef[f] += w[f] * a;
  }
  const float selfm = (j == i) ? 0.f : 1.f;  // nb_mask
#pragma unroll
  for (int f = 0; f < 64; ++f) ef[f] = fmaxf(ef[f], 0.f) * selfm;

  // ---- block-reduce edge_feat over j -> agg[b,i,:] ----
  for (int s = 1; s < 64; s <<= 1) {
#pragma unroll
    for (int f = 0; f < 64; ++f) ef[f] += __shfl_xor(ef[f], s, 64);
  }
  if (lane == 0) {
#pragma unroll
    for (int f = 0; f < 64; ++f) red[wave * 64 + f] = ef[f];
  }
  __syncthreads();
  if (tid < 64)
    aggO[node * 64 + tid] = red[tid] + red[64 + tid] + red[128 + tid] + red[192 + tid];
  __syncthreads();  // red reused below

  // ---- category MLPs -> factors ----
  float factors[16];
#pragma unroll
  for (int c = 0; c < 16; ++c) factors[c] = 0.f;
#pragma unroll
  for (int m = 0; m < 2; ++m) {
    const float catv = ldv(cat, (node * 256 + j) * 2 + m, flag);
    float a2[64];
    const u16* HaRm = HaR + 64 + m * 64;
    const u16* HbBm = HbB + (64 + m * 64) * 256;
#pragma unroll
    for (int o = 0; o < 64; ++o) a2[o] = bfld(HaRm[o]) + bfld(HbBm[o * 256 + j]);
    for (int c = 0; c < 16; ++c) {
      float dc = distT[c * 256 + tid];
      const float* w = WdT + ((m + 1) * 16 + c) * 64;
#pragma unroll
      for (int o = 0; o < 64; ++o) a2[o] += w[o] * dc;
    }
#pragma unroll
    for (int o = 0; o < 64; ++o) h1T[o * 256 + tid] = f2b(fmaxf(a2[o], 0.f));
    float ci16[16];
#pragma unroll
    for (int c = 0; c < 16; ++c) ci16[c] = ws[WS_BC2 + m * 16 + c];
#pragma unroll 2
    for (int o = 0; o < 64; ++o) {
      float a = bfld(h1T[o * 256 + tid]);
      const float* w = Wc2T + (m * 64 + o) * 16;
#pragma unroll
      for (int c = 0; c < 16; ++c) ci16[c] += w[c] * a;
    }
#pragma unroll
    for (int c = 0; c < 16; ++c) factors[c] += catv * fmaxf(ci16[c], 0.f);
  }

  // ---- factors MLP (f1, f2) ----
  float g[16];
#pragma unroll
  for (int c2 = 0; c2 < 16; ++c2) g[c2] = ws[WS_BF1 + c2];
#pragma unroll
  for (int c = 0; c < 16; ++c) {
    float fc = factors[c];
#pragma unroll
    for (int c2 = 0; c2 < 16; ++c2) g[c2] += Wf1T[c * 16 + c2] * fc;
  }
#pragma unroll
  for (int c2 = 0; c2 < 16; ++c2) g[c2] = fmaxf(g[c2], 0.f);
  float ff[16];
#pragma unroll
  for (int c2 = 0; c2 < 16; ++c2) ff[c2] = ws[WS_BF2 + c2];
#pragma unroll
  for (int c = 0; c < 16; ++c) {
    float fc = g[c];
#pragma unroll
    for (int c2 = 0; c2 < 16; ++c2) ff[c2] += Wf2T[c * 16 + c2] * fc;
  }
#pragma unroll
  for (int c2 = 0; c2 < 16; ++c2) ff[c2] = fmaxf(ff[c2], 0.f);

  // ---- coordinate aggregation: sum_j factors[c]*(ci - cj) ----
  float cacc[48];
#pragma unroll
  for (int c = 0; c < 16; ++c) {
#pragma unroll
    for (int d = 0; d < 3; ++d) {
      const int cd = c * 3 + d;
      float ci = cTb[cd * 256 + i];
      float cj = cTb[cd * 256 + j];
      cacc[cd] = ff[c] * (ci - cj);  // j==i contributes 0
    }
  }
  for (int s = 1; s < 64; s <<= 1) {
#pragma unroll
    for (int cd = 0; cd < 48; ++cd) cacc[cd] += __shfl_xor(cacc[cd], s, 64);
  }
  if (lane == 0) {
#pragma unroll
    for (int cd = 0; cd < 48; ++cd) red[wave * 64 + cd] = cacc[cd];
  }
  __syncthreads();
  if (tid < 48)
    caccO[node * 48 + tid] = red[tid] + red[64 + tid] + red[128 + tid] + red[192 + tid];
}

// ---------------- K1b: category passthrough (after k_edge) ------------------
__global__ void k_copycat(const void* __restrict__ cat, const float* __restrict__ ws,
                          void* __restrict__ outv) {
  const int flag = ((const int*)ws)[WS_FLAG];
  for (int i = blockIdx.x * blockDim.x + threadIdx.x; i < 1048576;
       i += gridDim.x * blockDim.x) {
    stv(outv, 229376 + i, ldv(cat, i, flag), flag);
  }
}

// ---------------- K2: node model -> h_out (2048 blocks x 64) ----------------
__global__ void k_node(const void* __restrict__ h, const float* __restrict__ ws,
                       void* __restrict__ outv) {
  const int node = blockIdx.x;
  const int f = threadIdx.x;  // 64
  const int flag = ((const int*)ws)[WS_FLAG];
  __shared__ float x[128];
  __shared__ float hid[64];
  const float hv = ldv(h, node * 64 + f, flag);
  x[f] = hv;
  x[64 + f] = ws[WS_AGG + node * 64 + f];
  __syncthreads();
  float s = ws[WS_BN1 + f];
  for (int k = 0; k < 128; ++k) s += ws[WS_WN1T + k * 64 + f] * x[k];
  hid[f] = fmaxf(s, 0.f);
  __syncthreads();
  float s2 = ws[WS_BN2 + f];
  for (int o = 0; o < 64; ++o) s2 += ws[WS_WN2T + o * 64 + f] * hid[o];
  stv(outv, node * 64 + f, hv + s2, flag);
}

// ---------------- K3: coord pipeline -> coord_out (8 blocks x 256) ----------
__global__ __launch_bounds__(256) void k_coord(const void* __restrict__ coord,
                                               const void* __restrict__ vel,
                                               const void* __restrict__ Wcv,
                                               const void* __restrict__ Wql,
                                               const void* __restrict__ Wkl,
                                               const float* __restrict__ ws,
                                               void* __restrict__ outv) {
  const int b = blockIdx.x;
  const int n = threadIdx.x;       // one node per thread
  const int node = b * 256 + n;
  const int wave = n >> 6, lane = n & 63;
  const int flag = ((const int*)ws)[WS_FLAG];
  __shared__ float wcv[256], wql[256], wkl[256];
  __shared__ float redm[16];
  wcv[n] = ldv(Wcv, n, flag);
  wql[n] = ldv(Wql, n, flag);
  wkl[n] = ldv(Wkl, n, flag);

  float cf[48];
#pragma unroll
  for (int cd = 0; cd < 48; ++cd) cf[cd] = ldv(coord, node * 48 + cd, flag);

  // mean over (n, c) per d of original coord
  float s0 = 0.f, s1 = 0.f, s2 = 0.f;
#pragma unroll
  for (int c = 0; c < 16; ++c) { s0 += cf[c * 3]; s1 += cf[c * 3 + 1]; s2 += cf[c * 3 + 2]; }
  for (int s = 1; s < 64; s <<= 1) {
    s0 += __shfl_xor(s0, s, 64); s1 += __shfl_xor(s1, s, 64); s2 += __shfl_xor(s2, s, 64);
  }
  if (lane == 0) { redm[wave * 4] = s0; redm[wave * 4 + 1] = s1; redm[wave * 4 + 2] = s2; }
  __syncthreads();
  const float m0 = (redm[0] + redm[4] + redm[8] + redm[12]) * (1.f / 4096.f);
  const float m1 = (redm[1] + redm[5] + redm[9] + redm[13]) * (1.f / 4096.f);
  const float m2 = (redm[2] + redm[6] + redm[10] + redm[14]) * (1.f / 4096.f);
  __syncthreads();  // redm reused

  float velf[48];
#pragma unroll
  for (int cd = 0; cd < 48; ++cd) velf[cd] = ldv(vel, node * 48 + cd, flag);

  // attention update + factor aggregation + velocity term
  float c3[48];
#pragma unroll
  for (int c = 0; c < 16; ++c) {
    const float at = ws[WS_ATT + node * 16 + c];
#pragma unroll
    for (int d = 0; d < 3; ++d) {
      const int cd = c * 3 + d;
      const float md = (d == 0) ? m0 : ((d == 1) ? m1 : m2);
      float v = cf[cd] - md;
      float cc = at * v + cf[cd];                  // inner attention
      cc += ws[WS_CAC + node * 48 + cd];           // + sum_j factors*coord_diff
      float a = cc;
#pragma unroll
      for (int cp = 0; cp < 16; ++cp) a += velf[cp * 3 + d] * wcv[c * 16 + cp];
      c3[cd] = a;
    }
  }

  // cm = mean over (n, c) of updated coord
  float t0 = 0.f, t1 = 0.f, t2 = 0.f;
#pragma unroll
  for (int c = 0; c < 16; ++c) { t0 += c3[c * 3]; t1 += c3[c * 3 + 1]; t2 += c3[c * 3 + 2]; }
  for (int s = 1; s < 64; s <<= 1) {
    t0 += __shfl_xor(t0, s, 64); t1 += __shfl_xor(t1, s, 64); t2 += __shfl_xor(t2, s, 64);
  }
  if (lane == 0) { redm[wave * 4] = t0; redm[wave * 4 + 1] = t1; redm[wave * 4 + 2] = t2; }
  __syncthreads();
  const float cm0 = (redm[0] + redm[4] + redm[8] + redm[12]) * (1.f / 4096.f);
  const float cm1 = (redm[1] + redm[5] + redm[9] + redm[13]) * (1.f / 4096.f);
  const float cm2 = (redm[2] + redm[6] + redm[10] + redm[14]) * (1.f / 4096.f);

  float cc[48];
#pragma unroll
  for (int c = 0; c < 16; ++c) {
    cc[c * 3]     = c3[c * 3]     - cm0;
    cc[c * 3 + 1] = c3[c * 3 + 1] - cm1;
    cc[c * 3 + 2] = c3[c * 3 + 2] - cm2;
  }

  // non-linear equivariant update
#pragma unroll
  for (int o = 0; o < 16; ++o) {
    float q[3], kv[3];
#pragma unroll
    for (int d = 0; d < 3; ++d) {
      float sq = 0.f, sk = 0.f;
#pragma unroll
      for (int cp = 0; cp < 16; ++cp) {
        sq += cc[cp * 3 + d] * wql[o * 16 + cp];
        sk += cc[cp * 3 + d] * wkl[o * 16 + cp];
      }
      q[d] = sq; kv[d] = sk;
    }
    const float prod = q[0] * kv[0] + q[1] * kv[1] + q[2] * kv[2];
    const float kns  = kv[0] * kv[0] + kv[1] * kv[1] + kv[2] * kv[2];
    const float w = prod / (kns + EPSV);
#pragma unroll
    for (int d = 0; d < 3; ++d) {
      const float cmd = (d == 0) ? cm0 : ((d == 1) ? cm1 : cm2);
      float val = (prod >= 0.f) ? q[d] : (q[d] - w * kv[d]);
      stv(outv, 131072 + node * 48 + o * 3 + d, val + cmd, flag);
    }
  }
}

// ---------------- launch ----------------------------------------------------
extern "C" void kernel_launch(void* const* d_in, const int* in_sizes, int n_in,
                              void* d_out, int out_size, void* d_ws, size_t ws_size,
                              hipStream_t stream) {
  (void)in_sizes; (void)n_in; (void)out_size; (void)ws_size;
  const void* h    = d_in[0];
  const void* coord= d_in[1];
  const void* vel  = d_in[2];
  const void* cat  = d_in[3];
  const void* Wcv  = d_in[4];
  const void* We1  = d_in[5];
  const void* be1  = d_in[6];
  const void* We2  = d_in[7];
  const void* be2  = d_in[8];
  const void* Wc1  = d_in[9];
  const void* bc1  = d_in[10];
  const void* Wc2  = d_in[11];
  const void* bc2  = d_in[12];
  const void* Wf1  = d_in[13];
  const void* bf1v = d_in[14];
  const void* Wf2  = d_in[15];
  const void* bf2v = d_in[16];
  const void* Wn1  = d_in[17];
  const void* bn1  = d_in[18];
  const void* Wn2  = d_in[19];
  const void* bn2  = d_in[20];
  const void* Wql  = d_in[21];
  const void* Wkl  = d_in[22];
  const void* Wqm  = d_in[23];
  const void* bqm  = d_in[24];
  float* ws = (float*)d_ws;

  k_prep_w<<<1, 256, 0, stream>>>(h, We1, Wc1, We2, be2, Wc2, bc2, Wf1, bf1v,
                                  Wf2, bf2v, Wn1, bn1, Wn2, bn2, ws);
  k_prep_node<<<2048, 64, 0, stream>>>(h, coord, be1, bc1, Wqm, bqm, ws, d_out);
  k_edge<<<2048, 256, 0, stream>>>(cat, ws, d_out);
  k_copycat<<<1024, 256, 0, stream>>>(cat, ws, d_out);  // after k_edge: frees scratch
  k_node<<<2048, 64, 0, stream>>>(h, ws, d_out);
  k_coord<<<8, 256, 0, stream>>>(coord, vel, Wcv, Wql, Wkl, ws, d_out);
}

// Round 3
// 581.603 us; speedup vs baseline: 1.2778x; 1.2778x over previous
//
#include <hip/hip_runtime.h>

typedef unsigned short u16;

// Problem constants: B=8, N=256, F=64, C=16, K=2
#define EPSV 1e-4f

// Output element offsets: h_out [0,131072) coord_out [131072,229376) category [229376,1277952)
// The category out-region is scratch for HA/HBT2 (bf16) until k_copycat runs.

// ---------------- ws layout (fp32 elements), total ~1.55 MB ----------------
static constexpr int WS_FLAG = 0;                      // int flag: 1=bf16 inputs, 0=fp32
static constexpr int WS_ATT  = 16;                     // [2048][16] relu(W_qm h + b_qm)
static constexpr int WS_CT   = WS_ATT + 2048 * 16;     // [8][48][256] coord transposed fp32
static constexpr int WS_AGG  = WS_CT  + 8 * 48 * 256;  // [2048][64] sum_j edge_feat (j!=i)
static constexpr int WS_CAC  = WS_AGG + 2048 * 64;     // [2048][48] sum_j factors*(ci-cj)
static constexpr int WS_WHAT = WS_CAC + 2048 * 48;     // [64 k][192 o] W cols 0:64 (h_i part)
static constexpr int WS_WHBT = WS_WHAT + 64 * 192;     // [64 k][192 o] W cols 64:128 (h_j part)
static constexpr int WS_WDT  = WS_WHBT + 64 * 192;     // [3 reg][64 o][16 c] W cols 128:144
static constexpr int WS_WE2T = WS_WDT  + 3 * 64 * 16;  // [64 o][64 f]  W_e2^T
static constexpr int WS_WC2T = WS_WE2T + 64 * 64;      // [2 m][64 o][16 c] W_cat2^T
static constexpr int WS_WF1T = WS_WC2T + 2 * 64 * 16;  // [16 c][16 c2] W_f1^T
static constexpr int WS_WF2T = WS_WF1T + 256;          // [16][16]
static constexpr int WS_WN1T = WS_WF2T + 256;          // [128 k][64 f] W_n1^T
static constexpr int WS_WN2T = WS_WN1T + 128 * 64;     // [64 o][64 f]  W_n2^T
static constexpr int WS_BE2  = WS_WN2T + 64 * 64;      // [64]
static constexpr int WS_BC2  = WS_BE2 + 64;            // [32]
static constexpr int WS_BF1  = WS_BC2 + 32;            // [16]
static constexpr int WS_BF2  = WS_BF1 + 16;            // [16]
static constexpr int WS_BN1  = WS_BF2 + 16;            // [64]
static constexpr int WS_BN2  = WS_BN1 + 64;            // [64]

static __device__ __forceinline__ float bfld(u16 v) {
  return __uint_as_float(((unsigned)v) << 16);
}
static __device__ __forceinline__ u16 f2b(float x) {  // round-to-nearest-even
  unsigned u = __float_as_uint(x);
  u += 0x7FFFu + ((u >> 16) & 1u);
  return (u16)(u >> 16);
}
static __device__ __forceinline__ float ldv(const void* p, int i, int flag) {
  return flag ? bfld(((const u16*)p)[i]) : ((const float*)p)[i];
}
static __device__ __forceinline__ void stv(void* p, int i, float v, int flag) {
  if (flag) ((u16*)p)[i] = f2b(v);
  else      ((float*)p)[i] = v;
}
static __device__ __forceinline__ u16* scratchHA(void* outv, int flag) {
  return (u16*)((char*)outv + (size_t)229376 * (flag ? 2 : 4));
}
static __device__ __forceinline__ int sniff_flag(const void* h) {
  const u16* hu = (const u16*)h;
  int cnt = 0;
  for (int i = 0; i < 128; ++i) {
    unsigned e = (hu[i] >> 7) & 0xFFu;
    if ((e >= 100u && e <= 150u) || hu[i] == 0) ++cnt;
  }
  return (cnt >= 112) ? 1 : 0;
}

// ---------------- K00: dtype sniff + weight transposes (8 blocks) -----------
__global__ void k_prep_w(const void* __restrict__ h,
                         const void* __restrict__ We1, const void* __restrict__ Wc1,
                         const void* __restrict__ We2, const void* __restrict__ be2,
                         const void* __restrict__ Wc2, const void* __restrict__ bc2,
                         const void* __restrict__ Wf1, const void* __restrict__ bf1,
                         const void* __restrict__ Wf2, const void* __restrict__ bf2,
                         const void* __restrict__ Wn1, const void* __restrict__ bn1,
                         const void* __restrict__ Wn2, const void* __restrict__ bn2,
                         float* __restrict__ ws) {
  const int t = blockIdx.x * 256 + threadIdx.x;  // 8*256 = 2048 threads
  const int STR = 2048;
  __shared__ int sflag;
  if (threadIdx.x == 0) {
    sflag = sniff_flag(h);
    if (blockIdx.x == 0) ((int*)ws)[WS_FLAG] = sflag;
  }
  __syncthreads();
  const int flag = sflag;

  // stacked layer-1 weights: o<64 -> W_e1[o], o in 64..191 -> W_cat1[o-64]
  for (int idx = t; idx < 64 * 192; idx += STR) {
    int k = idx / 192, o = idx % 192;
    const void* src = (o < 64) ? We1 : Wc1;
    const int roff = ((o < 64) ? o : (o - 64)) * 144;
    ws[WS_WHAT + idx] = ldv(src, roff + k, flag);
    ws[WS_WHBT + idx] = ldv(src, roff + 64 + k, flag);
  }
  for (int idx = t; idx < 3 * 64 * 16; idx += STR) {  // [reg][o][c], cols 128:144
    int r = idx / 1024, o = (idx >> 4) & 63, c = idx & 15;
    const void* src = (r == 0) ? We1 : Wc1;
    const int roff = ((r == 0) ? o : ((r - 1) * 64 + o)) * 144;
    ws[WS_WDT + idx] = ldv(src, roff + 128 + c, flag);
  }
  for (int idx = t; idx < 64 * 64; idx += STR) {      // We2T[o][f] = We2[f][o]
    int o = idx >> 6, f = idx & 63;
    ws[WS_WE2T + idx] = ldv(We2, f * 64 + o, flag);
  }
  for (int idx = t; idx < 2 * 64 * 16; idx += STR) {  // Wc2T[m][o][c] = Wc2[m][c][o]
    int m = idx / 1024, o = (idx >> 4) & 63, c = idx & 15;
    ws[WS_WC2T + idx] = ldv(Wc2, (m * 16 + c) * 64 + o, flag);
  }
  if (t < 256) {
    int c = t >> 4, c2 = t & 15;  // Wf1T[c][c2] = Wf1[c2][c]
    ws[WS_WF1T + t] = ldv(Wf1, c2 * 16 + c, flag);
    ws[WS_WF2T + t] = ldv(Wf2, c2 * 16 + c, flag);
  }
  for (int idx = t; idx < 128 * 64; idx += STR) {     // Wn1T[k][f] = Wn1[f][k]
    int k = idx >> 6, f = idx & 63;
    ws[WS_WN1T + idx] = ldv(Wn1, f * 128 + k, flag);
  }
  for (int idx = t; idx < 64 * 64; idx += STR) {      // Wn2T[o][f] = Wn2[f][o]
    int o = idx >> 6, f = idx & 63;
    ws[WS_WN2T + idx] = ldv(Wn2, f * 64 + o, flag);
  }
  if (t < 64) ws[WS_BE2 + t] = ldv(be2, t, flag);
  if (t < 32) ws[WS_BC2 + t] = ldv(bc2, t, flag);
  if (t < 16) { ws[WS_BF1 + t] = ldv(bf1, t, flag); ws[WS_BF2 + t] = ldv(bf2, t, flag); }
  if (t >= 64 && t < 128)  ws[WS_BN1 + t - 64]  = ldv(bn1, t - 64, flag);
  if (t >= 128 && t < 192) ws[WS_BN2 + t - 128] = ldv(bn2, t - 128, flag);
}

// ---------------- K0: per-node precompute (2048 blocks x 64) ----------------
__global__ void k_prep_node(const void* __restrict__ h, const void* __restrict__ coord,
                            const void* __restrict__ be1, const void* __restrict__ bc1,
                            const void* __restrict__ Wqm, const void* __restrict__ bqm,
                            float* __restrict__ ws, void* __restrict__ outv) {
  const int node = blockIdx.x;            // b*256 + n
  const int b = node >> 8, n = node & 255;
  const int lane = threadIdx.x;           // 64
  const int flag = ((const int*)ws)[WS_FLAG];
  u16* HA16 = scratchHA(outv, flag);      // [2048][192] bf16
  u16* HB16 = HA16 + 2048 * 192;          // [8][96 op][256 n][2 parity] bf16
  __shared__ float hF[64];
  hF[lane] = ldv(h, node * 64 + lane, flag);
  __syncthreads();
  const float* __restrict__ WhaT = ws + WS_WHAT;
  const float* __restrict__ WhbT = ws + WS_WHBT;
#pragma unroll
  for (int r = 0; r < 3; ++r) {
    const int o = r * 64 + lane;
    float sa = (o < 64) ? ldv(be1, o, flag) : ldv(bc1, o - 64, flag);  // fold bias
    float sb = 0.f;
    for (int k = 0; k < 64; ++k) {
      float hk = hF[k];
      sa += WhaT[k * 192 + o] * hk;
      sb += WhbT[k * 192 + o] * hk;
    }
    HA16[node * 192 + o] = f2b(sa);
    HB16[((b * 96 + (o >> 1)) * 256 + n) * 2 + (o & 1)] = f2b(sb);
  }
  if (lane < 16) {  // att = relu(W_qm h + b_qm)
    float s = ldv(bqm, lane, flag);
    for (int f = 0; f < 64; ++f) s += ldv(Wqm, lane * 64 + f, flag) * hF[f];
    ws[WS_ATT + node * 16 + lane] = fmaxf(s, 0.f);
  }
  if (lane < 48) {  // coord transposed to [b][cd][n] fp32
    ws[WS_CT + (b * 48 + lane) * 256 + n] = ldv(coord, node * 48 + lane, flag);
  }
}

// Reduce-scatter butterfly over a 64-payload array: on return, lane l holds
// sum over the wave's 64 lanes of payload index l. Cost: 63 swz + 63 add.
static __device__ __forceinline__ void rs_reduce64(float (&a)[64], int lane) {
#pragma unroll
  for (int s = 0; s < 6; ++s) {
    const int lb = (lane >> s) & 1;
    const int cnt = 64 >> (s + 1);
#pragma unroll
    for (int i2 = 0; i2 < cnt; ++i2) {
      const float lo = a[2 * i2], hi = a[2 * i2 + 1];
      const float sent = lb ? lo : hi;
      const float kept = lb ? hi : lo;
      a[i2] = kept + __shfl_xor(sent, 1 << s, 64);
    }
  }
}

// ---------------- K1: edge kernel (2048 blocks x 256) -----------------------
// block = (b,i); thread = j. All MLP state lives in registers; LDS only for
// the wave-uniform Ha row / c_i column and the cross-wave reduction buffer.
__global__ __launch_bounds__(256, 4) void k_edge(const void* __restrict__ cat,
                                                 float* __restrict__ ws,
                                                 void* __restrict__ outv) {
  const int node = blockIdx.x;
  const int b = node >> 8, i = node & 255;
  const int tid = threadIdx.x;
  const int j = tid;
  const int wave = tid >> 6, lane = tid & 63;
  const int flag = ((const int*)ws)[WS_FLAG];
  const u16* HA16 = scratchHA(outv, flag);
  const unsigned* HBT2 = (const unsigned*)(HA16 + 2048 * 192);  // [8][96 op][256 j]

  __shared__ float sHa[192];
  __shared__ float sCi[48];
  __shared__ float red[4 * 64];

  const float* __restrict__ cTb  = ws + WS_CT + b * 48 * 256;
  const float* __restrict__ WdT  = ws + WS_WDT;   // [3*64 go][16 c]
  const float* __restrict__ We2T = ws + WS_WE2T;  // [o][f]
  float* __restrict__ aggO  = ws + WS_AGG;
  float* __restrict__ caccO = ws + WS_CAC;

  if (tid < 192) sHa[tid] = bfld(HA16[node * 192 + tid]);
  if (tid >= 192 && tid < 240) sCi[tid - 192] = cTb[(tid - 192) * 256 + i];
  __syncthreads();

  // ---- pairwise channel distances (registers) ----
  float dr[16];
#pragma unroll
  for (int c = 0; c < 16; ++c) {
    float s = 0.f;
#pragma unroll
    for (int d = 0; d < 3; ++d) {
      const int cd = c * 3 + d;
      const float df = sCi[cd] - cTb[cd * 256 + j];
      s += df * df;
    }
    dr[c] = sqrtf(s);
  }

  // ---- edge MLP: layer1 streamed into layer2 accumulators ----
  float ef[64];
#pragma unroll
  for (int f = 0; f < 64; ++f) ef[f] = ws[WS_BE2 + f];
  {
    const unsigned* hb0 = HBT2 + (size_t)(b * 96) * 256 + j;
#pragma unroll 1
    for (int op = 0; op < 32; ++op) {
      const unsigned pk = hb0[op * 256];
      const int o0 = 2 * op;
      {
        float a = sHa[o0] + bfld((u16)(pk & 0xFFFFu));
        const float* w = WdT + o0 * 16;
#pragma unroll
        for (int c = 0; c < 16; ++c) a += w[c] * dr[c];
        a = fmaxf(a, 0.f);
        const float* w2 = We2T + o0 * 64;
#pragma unroll
        for (int f = 0; f < 64; ++f) ef[f] += w2[f] * a;
      }
      {
        float a = sHa[o0 + 1] + bfld((u16)(pk >> 16));
        const float* w = WdT + (o0 + 1) * 16;
#pragma unroll
        for (int c = 0; c < 16; ++c) a += w[c] * dr[c];
        a = fmaxf(a, 0.f);
        const float* w2 = We2T + (o0 + 1) * 64;
#pragma unroll
        for (int f = 0; f < 64; ++f) ef[f] += w2[f] * a;
      }
    }
  }
  const float selfm = (j == i) ? 0.f : 1.f;  // nb_mask
#pragma unroll
  for (int f = 0; f < 64; ++f) ef[f] = fmaxf(ef[f], 0.f) * selfm;

  // ---- reduce over j -> agg[b,i,:] ----
  rs_reduce64(ef, lane);
  red[wave * 64 + lane] = ef[0];
  __syncthreads();
  if (tid < 64)
    aggO[node * 64 + tid] = red[tid] + red[64 + tid] + red[128 + tid] + red[192 + tid];

  // ---- category MLPs -> factors (streamed, registers) ----
  float cv0, cv1;
  if (flag) {
    const unsigned p = ((const unsigned*)cat)[node * 256 + j];
    cv0 = bfld((u16)(p & 0xFFFFu)); cv1 = bfld((u16)(p >> 16));
  } else {
    const float2 p = ((const float2*)cat)[node * 256 + j];
    cv0 = p.x; cv1 = p.y;
  }
  float factors[16];
#pragma unroll
  for (int c = 0; c < 16; ++c) factors[c] = 0.f;
#pragma unroll
  for (int m = 0; m < 2; ++m) {
    const float catv = m ? cv1 : cv0;
    float ci16[16];
#pragma unroll
    for (int c = 0; c < 16; ++c) ci16[c] = ws[WS_BC2 + m * 16 + c];
    const unsigned* hbm = HBT2 + (size_t)(b * 96 + 32 + m * 32) * 256 + j;
#pragma unroll 1
    for (int op = 0; op < 32; ++op) {
      const unsigned pk = hbm[op * 256];
      const int ol = 2 * op;               // local o in 0..63
      const int go = 64 + m * 64 + ol;     // global stacked row
      {
        float a = sHa[go] + bfld((u16)(pk & 0xFFFFu));
        const float* w = WdT + go * 16;
#pragma unroll
        for (int c = 0; c < 16; ++c) a += w[c] * dr[c];
        a = fmaxf(a, 0.f);
        const float* w2 = ws + WS_WC2T + (m * 64 + ol) * 16;
#pragma unroll
        for (int c = 0; c < 16; ++c) ci16[c] += w2[c] * a;
      }
      {
        float a = sHa[go + 1] + bfld((u16)(pk >> 16));
        const float* w = WdT + (go + 1) * 16;
#pragma unroll
        for (int c = 0; c < 16; ++c) a += w[c] * dr[c];
        a = fmaxf(a, 0.f);
        const float* w2 = ws + WS_WC2T + (m * 64 + ol + 1) * 16;
#pragma unroll
        for (int c = 0; c < 16; ++c) ci16[c] += w2[c] * a;
      }
    }
#pragma unroll
    for (int c = 0; c < 16; ++c) factors[c] += catv * fmaxf(ci16[c], 0.f);
  }

  // ---- factors MLP (f1, f2) ----
  float g[16];
#pragma unroll
  for (int c2 = 0; c2 < 16; ++c2) g[c2] = ws[WS_BF1 + c2];
#pragma unroll
  for (int c = 0; c < 16; ++c) {
    const float fc = factors[c];
    const float* w = ws + WS_WF1T + c * 16;
#pragma unroll
    for (int c2 = 0; c2 < 16; ++c2) g[c2] += w[c2] * fc;
  }
#pragma unroll
  for (int c2 = 0; c2 < 16; ++c2) g[c2] = fmaxf(g[c2], 0.f);
  float ff[16];
#pragma unroll
  for (int c2 = 0; c2 < 16; ++c2) ff[c2] = ws[WS_BF2 + c2];
#pragma unroll
  for (int c = 0; c < 16; ++c) {
    const float fc = g[c];
    const float* w = ws + WS_WF2T + c * 16;
#pragma unroll
    for (int c2 = 0; c2 < 16; ++c2) ff[c2] += w[c2] * fc;
  }
#pragma unroll
  for (int c2 = 0; c2 < 16; ++c2) ff[c2] = fmaxf(ff[c2], 0.f);

  // ---- coordinate aggregation: sum_j factors[c]*(ci - cj) ----
  __syncthreads();  // red re-use: ensure agg consumers finished
  float cw[64];
#pragma unroll
  for (int cd = 0; cd < 48; ++cd)
    cw[cd] = ff[cd / 3] * (sCi[cd] - cTb[cd * 256 + j]);  // j==i contributes 0
#pragma unroll
  for (int cd = 48; cd < 64; ++cd) cw[cd] = 0.f;
  rs_reduce64(cw, lane);
  red[wave * 64 + lane] = cw[0];
  __syncthreads();
  if (tid < 48)
    caccO[node * 48 + tid] = red[tid] + red[64 + tid] + red[128 + tid] + red[192 + tid];
}

// ---------------- K1b: category passthrough (after k_edge) ------------------
__global__ void k_copycat(const void* __restrict__ cat, const float* __restrict__ ws,
                          void* __restrict__ outv) {
  const int flag = ((const int*)ws)[WS_FLAG];
  const int idx = blockIdx.x * 256 + threadIdx.x;  // 1024*256 = 262144 threads
  if (flag) {  // 1048576 bf16 = 2 MB = 262144 x 8B
    ((uint2*)((char*)outv + 458752))[idx] = ((const uint2*)cat)[idx];
  } else {     // 4 MB = 262144 x 16B
    ((uint4*)((char*)outv + 917504))[idx] = ((const uint4*)cat)[idx];
  }
}

// ---------------- K2: node model -> h_out (2048 blocks x 64) ----------------
__global__ void k_node(const void* __restrict__ h, const float* __restrict__ ws,
                       void* __restrict__ outv) {
  const int node = blockIdx.x;
  const int f = threadIdx.x;  // 64
  const int flag = ((const int*)ws)[WS_FLAG];
  __shared__ float x[128];
  __shared__ float hid[64];
  const float hv = ldv(h, node * 64 + f, flag);
  x[f] = hv;
  x[64 + f] = ws[WS_AGG + node * 64 + f];
  __syncthreads();
  float s = ws[WS_BN1 + f];
  for (int k = 0; k < 128; ++k) s += ws[WS_WN1T + k * 64 + f] * x[k];
  hid[f] = fmaxf(s, 0.f);
  __syncthreads();
  float s2 = ws[WS_BN2 + f];
  for (int o = 0; o < 64; ++o) s2 += ws[WS_WN2T + o * 64 + f] * hid[o];
  stv(outv, node * 64 + f, hv + s2, flag);
}

// ---------------- K3: coord pipeline -> coord_out (8 blocks x 256) ----------
__global__ __launch_bounds__(256) void k_coord(const void* __restrict__ coord,
                                               const void* __restrict__ vel,
                                               const void* __restrict__ Wcv,
                                               const void* __restrict__ Wql,
                                               const void* __restrict__ Wkl,
                                               const float* __restrict__ ws,
                                               void* __restrict__ outv) {
  const int b = blockIdx.x;
  const int n = threadIdx.x;       // one node per thread
  const int node = b * 256 + n;
  const int wave = n >> 6, lane = n & 63;
  const int flag = ((const int*)ws)[WS_FLAG];
  __shared__ float wcv[256], wql[256], wkl[256];
  __shared__ float redm[16];
  wcv[n] = ldv(Wcv, n, flag);
  wql[n] = ldv(Wql, n, flag);
  wkl[n] = ldv(Wkl, n, flag);

  float cf[48];
#pragma unroll
  for (int cd = 0; cd < 48; ++cd) cf[cd] = ldv(coord, node * 48 + cd, flag);

  // mean over (n, c) per d of original coord
  float s0 = 0.f, s1 = 0.f, s2 = 0.f;
#pragma unroll
  for (int c = 0; c < 16; ++c) { s0 += cf[c * 3]; s1 += cf[c * 3 + 1]; s2 += cf[c * 3 + 2]; }
  for (int s = 1; s < 64; s <<= 1) {
    s0 += __shfl_xor(s0, s, 64); s1 += __shfl_xor(s1, s, 64); s2 += __shfl_xor(s2, s, 64);
  }
  if (lane == 0) { redm[wave * 4] = s0; redm[wave * 4 + 1] = s1; redm[wave * 4 + 2] = s2; }
  __syncthreads();
  const float m0 = (redm[0] + redm[4] + redm[8] + redm[12]) * (1.f / 4096.f);
  const float m1 = (redm[1] + redm[5] + redm[9] + redm[13]) * (1.f / 4096.f);
  const float m2 = (redm[2] + redm[6] + redm[10] + redm[14]) * (1.f / 4096.f);
  __syncthreads();  // redm reused

  float velf[48];
#pragma unroll
  for (int cd = 0; cd < 48; ++cd) velf[cd] = ldv(vel, node * 48 + cd, flag);

  // attention update + factor aggregation + velocity term
  float c3[48];
#pragma unroll
  for (int c = 0; c < 16; ++c) {
    const float at = ws[WS_ATT + node * 16 + c];
#pragma unroll
    for (int d = 0; d < 3; ++d) {
      const int cd = c * 3 + d;
      const float md = (d == 0) ? m0 : ((d == 1) ? m1 : m2);
      float v = cf[cd] - md;
      float cc = at * v + cf[cd];                  // inner attention
      cc += ws[WS_CAC + node * 48 + cd];           // + sum_j factors*coord_diff
      float a = cc;
#pragma unroll
      for (int cp = 0; cp < 16; ++cp) a += velf[cp * 3 + d] * wcv[c * 16 + cp];
      c3[cd] = a;
    }
  }

  // cm = mean over (n, c) of updated coord
  float t0 = 0.f, t1 = 0.f, t2 = 0.f;
#pragma unroll
  for (int c = 0; c < 16; ++c) { t0 += c3[c * 3]; t1 += c3[c * 3 + 1]; t2 += c3[c * 3 + 2]; }
  for (int s = 1; s < 64; s <<= 1) {
    t0 += __shfl_xor(t0, s, 64); t1 += __shfl_xor(t1, s, 64); t2 += __shfl_xor(t2, s, 64);
  }
  if (lane == 0) { redm[wave * 4] = t0; redm[wave * 4 + 1] = t1; redm[wave * 4 + 2] = t2; }
  __syncthreads();
  const float cm0 = (redm[0] + redm[4] + redm[8] + redm[12]) * (1.f / 4096.f);
  const float cm1 = (redm[1] + redm[5] + redm[9] + redm[13]) * (1.f / 4096.f);
  const float cm2 = (redm[2] + redm[6] + redm[10] + redm[14]) * (1.f / 4096.f);

  float cc[48];
#pragma unroll
  for (int c = 0; c < 16; ++c) {
    cc[c * 3]     = c3[c * 3]     - cm0;
    cc[c * 3 + 1] = c3[c * 3 + 1] - cm1;
    cc[c * 3 + 2] = c3[c * 3 + 2] - cm2;
  }

  // non-linear equivariant update
#pragma unroll
  for (int o = 0; o < 16; ++o) {
    float q[3], kv[3];
#pragma unroll
    for (int d = 0; d < 3; ++d) {
      float sq = 0.f, sk = 0.f;
#pragma unroll
      for (int cp = 0; cp < 16; ++cp) {
        sq += cc[cp * 3 + d] * wql[o * 16 + cp];
        sk += cc[cp * 3 + d] * wkl[o * 16 + cp];
      }
      q[d] = sq; kv[d] = sk;
    }
    const float prod = q[0] * kv[0] + q[1] * kv[1] + q[2] * kv[2];
    const float kns  = kv[0] * kv[0] + kv[1] * kv[1] + kv[2] * kv[2];
    const float w = prod / (kns + EPSV);
#pragma unroll
    for (int d = 0; d < 3; ++d) {
      const float cmd = (d == 0) ? cm0 : ((d == 1) ? cm1 : cm2);
      const float val = (prod >= 0.f) ? q[d] : (q[d] - w * kv[d]);
      stv(outv, 131072 + node * 48 + o * 3 + d, val + cmd, flag);
    }
  }
}

// ---------------- launch ----------------------------------------------------
extern "C" void kernel_launch(void* const* d_in, const int* in_sizes, int n_in,
                              void* d_out, int out_size, void* d_ws, size_t ws_size,
                              hipStream_t stream) {
  (void)in_sizes; (void)n_in; (void)out_size; (void)ws_size;
  const void* h    = d_in[0];
  const void* coord= d_in[1];
  const void* vel  = d_in[2];
  const void* cat  = d_in[3];
  const void* Wcv  = d_in[4];
  const void* We1  = d_in[5];
  const void* be1  = d_in[6];
  const void* We2  = d_in[7];
  const void* be2  = d_in[8];
  const void* Wc1  = d_in[9];
  const void* bc1  = d_in[10];
  const void* Wc2  = d_in[11];
  const void* bc2  = d_in[12];
  const void* Wf1  = d_in[13];
  const void* bf1v = d_in[14];
  const void* Wf2  = d_in[15];
  const void* bf2v = d_in[16];
  const void* Wn1  = d_in[17];
  const void* bn1  = d_in[18];
  const void* Wn2  = d_in[19];
  const void* bn2  = d_in[20];
  const void* Wql  = d_in[21];
  const void* Wkl  = d_in[22];
  const void* Wqm  = d_in[23];
  const void* bqm  = d_in[24];
  float* ws = (float*)d_ws;

  k_prep_w<<<8, 256, 0, stream>>>(h, We1, Wc1, We2, be2, Wc2, bc2, Wf1, bf1v,
                                  Wf2, bf2v, Wn1, bn1, Wn2, bn2, ws);
  k_prep_node<<<2048, 64, 0, stream>>>(h, coord, be1, bc1, Wqm, bqm, ws, d_out);
  k_edge<<<2048, 256, 0, stream>>>(cat, ws, d_out);
  k_copycat<<<1024, 256, 0, stream>>>(cat, ws, d_out);  // frees scratch region
  k_node<<<2048, 64, 0, stream>>>(h, ws, d_out);
  k_coord<<<8, 256, 0, stream>>>(coord, vel, Wcv, Wql, Wkl, ws, d_out);
}

// Round 5
// 315.211 us; speedup vs baseline: 2.3576x; 1.8451x over previous
//
#include <hip/hip_runtime.h>

typedef unsigned short u16;
typedef unsigned int u32;
typedef _Float16 f16;
typedef __attribute__((ext_vector_type(2))) _Float16 f16x2;
typedef __attribute__((ext_vector_type(4))) _Float16 f16x4;
typedef __attribute__((ext_vector_type(4))) float f32x4;

// Problem constants: B=8, N=256, F=64, C=16, K=2
#define EPSV 1e-4f

// Output element offsets: h_out [0,131072) coord_out [131072,229376) category [229376,1277952)
// Category out-region is scratch for HA/HBJ (f16) until the epilogue copies category in.

// ---------------- ws layout (fp32 slots) -----------------------------------
static constexpr int WS_FLAG = 0;                     // +16
static constexpr int WS_ATT  = 16;                    // [2048][16]
static constexpr int WS_CT   = 32784;                 // [8][48][256] coord^T fp32
static constexpr int WS_AGG  = 131088;                // [2048][64]
static constexpr int WS_CAC  = 262160;                // [2048][48]
static constexpr int WS_WN1T = 360464;                // [128 k][64 f] fp32
static constexpr int WS_WN2T = 368656;                // [64 o][64 f] fp32
static constexpr int WS_BN1  = 372752;                // [64]
static constexpr int WS_BN2  = 372816;                // [64]
static constexpr int WS_BIAS = 372880;                // be2[64]|bc2[32]|bf1[16]|bf2[16]
static constexpr int WS_GWD  = 373008;                // f16 [192 o'][16 c]   (1536 slots)
static constexpr int WS_GWE2 = 374544;                // f16 [64 f][64 o]     (2048)
static constexpr int WS_GWC2 = 376592;                // f16 [32 mc][64 o]    (1024)
static constexpr int WS_GWF1 = 377616;                // f16 [16][16]         (128)
static constexpr int WS_GWF2 = 377744;                // f16 [16][16]         (128)
// total 377872 f32 = 1.44 MB

static __device__ __forceinline__ float bfld(u16 v) {
  return __uint_as_float(((unsigned)v) << 16);
}
static __device__ __forceinline__ u16 f2b(float x) {  // RNE
  unsigned u = __float_as_uint(x);
  u += 0x7FFFu + ((u >> 16) & 1u);
  return (u16)(u >> 16);
}
static __device__ __forceinline__ float ldv(const void* p, int i, int flag) {
  return flag ? bfld(((const u16*)p)[i]) : ((const float*)p)[i];
}
static __device__ __forceinline__ void stv(void* p, int i, float v, int flag) {
  if (flag) ((u16*)p)[i] = f2b(v);
  else      ((float*)p)[i] = v;
}
static __device__ __forceinline__ f16* scratchHA(void* outv, int flag) {
  return (f16*)((char*)outv + (size_t)229376 * (flag ? 2 : 4));
}
static __device__ __forceinline__ int sniff_flag(const void* h) {
  const u16* hu = (const u16*)h;
  int cnt = 0;
  for (int i = 0; i < 128; ++i) {
    unsigned e = (hu[i] >> 7) & 0xFFu;
    if ((e >= 100u && e <= 150u) || hu[i] == 0) ++cnt;
  }
  return (cnt >= 112) ? 1 : 0;
}
static __device__ __forceinline__ f16x4 pack4(float a, float b, float c, float d) {
  const f16x2 lo = __builtin_bit_cast(f16x2, __builtin_amdgcn_cvt_pkrtz(a, b));
  const f16x2 hi = __builtin_bit_cast(f16x2, __builtin_amdgcn_cvt_pkrtz(c, d));
  f16x4 r; r[0] = lo[0]; r[1] = lo[1]; r[2] = hi[0]; r[3] = hi[1]; return r;
}

// ---------------- K0: per-node precompute + weight tables (2048 x 64) -------
__global__ void k_prep(const void* __restrict__ h, const void* __restrict__ coord,
                       const void* __restrict__ be1, const void* __restrict__ bc1,
                       const void* __restrict__ Wqm, const void* __restrict__ bqm,
                       const void* __restrict__ We1, const void* __restrict__ Wc1,
                       const void* __restrict__ We2, const void* __restrict__ be2,
                       const void* __restrict__ Wc2, const void* __restrict__ bc2,
                       const void* __restrict__ Wf1, const void* __restrict__ bf1,
                       const void* __restrict__ Wf2, const void* __restrict__ bf2,
                       const void* __restrict__ Wn1, const void* __restrict__ bn1,
                       const void* __restrict__ Wn2, const void* __restrict__ bn2,
                       float* __restrict__ ws, void* __restrict__ outv) {
  const int node = blockIdx.x;  // b*256 + n
  const int b = node >> 8, n = node & 255;
  const int lane = threadIdx.x; // 64
  __shared__ int sflag;
  __shared__ float hF[64];
  if (lane == 0) { sflag = sniff_flag(h); ((int*)ws)[WS_FLAG] = sflag; }
  __syncthreads();
  const int flag = sflag;
  hF[lane] = ldv(h, node * 64 + lane, flag);
  __syncthreads();
  f16* HA16 = scratchHA(outv, flag);  // [2048][192]
  f16* HBJ  = HA16 + 2048 * 192;      // [2048][192]
#pragma unroll
  for (int r = 0; r < 3; ++r) {
    const int o = r * 64 + lane;
    const void* Wsrc = (o < 64) ? We1 : Wc1;
    const int row = (o < 64) ? o : (o - 64);
    float sa = (o < 64) ? ldv(be1, o, flag) : ldv(bc1, o - 64, flag);  // fold bias
    float sb = 0.f;
    for (int k = 0; k < 64; ++k) {
      const float hk = hF[k];
      sa += ldv(Wsrc, row * 144 + k, flag) * hk;
      sb += ldv(Wsrc, row * 144 + 64 + k, flag) * hk;
    }
    HA16[node * 192 + o] = (f16)sa;
    HBJ[node * 192 + o]  = (f16)sb;
  }
  if (lane < 16) {  // att = relu(W_qm h + b_qm)
    float s = ldv(bqm, lane, flag);
    for (int f = 0; f < 64; ++f) s += ldv(Wqm, lane * 64 + f, flag) * hF[f];
    ws[WS_ATT + node * 16 + lane] = fmaxf(s, 0.f);
  }
  if (lane < 48) {  // coord^T [b][cd][n] fp32
    ws[WS_CT + (b * 48 + lane) * 256 + n] = ldv(coord, node * 48 + lane, flag);
  }
  // weight tables: blocks 0..31 (2048 threads total)
  if (blockIdx.x < 32) {
    const int g = blockIdx.x * 64 + lane;
    const int GS = 2048;
    f16* gwd  = (f16*)(ws + WS_GWD);
    f16* gwe2 = (f16*)(ws + WS_GWE2);
    f16* gwc2 = (f16*)(ws + WS_GWC2);
    f16* gwf1 = (f16*)(ws + WS_GWF1);
    f16* gwf2 = (f16*)(ws + WS_GWF2);
    for (int idx = g; idx < 3072; idx += GS) {  // [o'][c] <- cols 128..143
      const int o = idx >> 4, c = idx & 15;
      const void* src = (o < 64) ? We1 : Wc1;
      const int row = (o < 64) ? o : (o - 64);
      gwd[idx] = (f16)ldv(src, row * 144 + 128 + c, flag);
    }
    for (int idx = g; idx < 4096; idx += GS) gwe2[idx] = (f16)ldv(We2, idx, flag);
    for (int idx = g; idx < 2048; idx += GS) gwc2[idx] = (f16)ldv(Wc2, idx, flag);
    if (g < 256) { gwf1[g] = (f16)ldv(Wf1, g, flag); gwf2[g] = (f16)ldv(Wf2, g, flag); }
    for (int idx = g; idx < 8192; idx += GS) {  // Wn1T[k][f]
      const int k = idx >> 6, f = idx & 63;
      ws[WS_WN1T + idx] = ldv(Wn1, f * 128 + k, flag);
    }
    for (int idx = g; idx < 4096; idx += GS) {  // Wn2T[o][f]
      const int o = idx >> 6, f = idx & 63;
      ws[WS_WN2T + idx] = ldv(Wn2, f * 64 + o, flag);
    }
    if (g < 64)  ws[WS_BN1 + g] = ldv(bn1, g, flag);
    if (g < 64)  ws[WS_BN2 + g] = ldv(bn2, g, flag);
    if (g < 64)  ws[WS_BIAS + g] = ldv(be2, g, flag);
    if (g < 32)  ws[WS_BIAS + 64 + g] = ldv(bc2, g, flag);
    if (g < 16)  ws[WS_BIAS + 96 + g] = ldv(bf1, g, flag);
    if (g < 16)  ws[WS_BIAS + 112 + g] = ldv(bf2, g, flag);
  }
}

// ---------------- K1: MFMA edge kernel (2048 blocks x 256) ------------------
// All GEMMs transposed: C[out][j]. 16x16x16 f16 MFMA; C/D layout == next
// GEMM's B layout, so relu+pkrtz chains GEMMs in-register (no LDS repack).
__global__ __launch_bounds__(256, 4) void k_edge(const void* __restrict__ cat,
                                                 float* __restrict__ ws,
                                                 void* __restrict__ outv) {
  const int node = blockIdx.x, b = node >> 8, i = node & 255;
  const int tid = threadIdx.x;
  const int w = tid >> 6, lane = tid & 63, q = lane >> 4, l15 = lane & 15;
  const int flag = ((const int*)ws)[WS_FLAG];
  const f16* HA16 = scratchHA(outv, flag);
  const f16* HBJ  = HA16 + 2048 * 192;
  const float* __restrict__ cTb = ws + WS_CT + b * 48 * 256;

  // padded-stride LDS (strides picked for <=2-way bank conflicts, 8B aligned)
  __shared__ __align__(16) f16 sWd[192 * 20];
  __shared__ __align__(16) f16 sWe2[64 * 76];
  __shared__ __align__(16) f16 sWc2[32 * 76];
  __shared__ __align__(16) f16 sWf1[16 * 20];
  __shared__ __align__(16) f16 sWf2[16 * 20];
  __shared__ __align__(16) f16 distS[256 * 20];
  __shared__ float sHa[192];
  __shared__ float sB[128];
  __shared__ __align__(16) float red[256];

  {  // stage weight tables (u32 copies with pad remap)
    const u32* gwd = (const u32*)(ws + WS_GWD);
    for (int idx = tid; idx < 1536; idx += 256) {
      const int r = idx >> 3, c = idx & 7;
      *(u32*)&sWd[r * 20 + c * 2] = gwd[idx];
    }
    const u32* gwe = (const u32*)(ws + WS_GWE2);
    for (int idx = tid; idx < 2048; idx += 256) {
      const int r = idx >> 5, c = idx & 31;
      *(u32*)&sWe2[r * 76 + c * 2] = gwe[idx];
    }
    const u32* gwc = (const u32*)(ws + WS_GWC2);
    for (int idx = tid; idx < 1024; idx += 256) {
      const int r = idx >> 5, c = idx & 31;
      *(u32*)&sWc2[r * 76 + c * 2] = gwc[idx];
    }
    if (tid < 128) {
      const int r = tid >> 3, c = tid & 7;
      *(u32*)&sWf1[r * 20 + c * 2] = ((const u32*)(ws + WS_GWF1))[tid];
      *(u32*)&sWf2[r * 20 + c * 2] = ((const u32*)(ws + WS_GWF2))[tid];
    }
    if (tid < 192) sHa[tid] = (float)HA16[node * 192 + tid];
    if (tid < 128) sB[tid] = ws[WS_BIAS + tid];
  }
  {  // distances (thread = j), stage as f16 [j][16c] pad-20
    float dr[16];
#pragma unroll
    for (int c = 0; c < 16; ++c) {
      float s = 0.f;
#pragma unroll
      for (int d = 0; d < 3; ++d) {
        const int cd = c * 3 + d;
        const float df = cTb[cd * 256 + i] - cTb[cd * 256 + tid];
        s += df * df;
      }
      dr[c] = sqrtf(s);
    }
#pragma unroll
    for (int kk = 0; kk < 4; ++kk)
      *(f16x4*)&distS[tid * 20 + kk * 4] =
          pack4(dr[4 * kk], dr[4 * kk + 1], dr[4 * kk + 2], dr[4 * kk + 3]);
  }
  __syncthreads();

  int jj[4]; float mjt[4]; f16x4 dfr[4];
#pragma unroll
  for (int jt = 0; jt < 4; ++jt) {
    jj[jt] = w * 64 + jt * 16 + l15;
    mjt[jt] = (jj[jt] == i) ? 0.f : 1.f;
    dfr[jt] = *(const f16x4*)&distS[jj[jt] * 20 + q * 4];  // B[k=c][n=j]
  }

  // ---- phase 1: e2 GEMM chain, C2[f][j] over K=64 -------------------------
  f32x4 C2[4][4];
#pragma unroll
  for (int ft = 0; ft < 4; ++ft)
#pragma unroll
    for (int jt = 0; jt < 4; ++jt) C2[ft][jt] = (f32x4){0.f, 0.f, 0.f, 0.f};
#pragma unroll
  for (int og = 0; og < 4; ++og) {
    const f16x4 wd = *(const f16x4*)&sWd[(og * 16 + l15) * 20 + q * 4];  // A[o'][c]
    f16x4 af[4];
#pragma unroll
    for (int jt = 0; jt < 4; ++jt) {
      const f16x4 hb = *(const f16x4*)(HBJ + (b * 256 + jj[jt]) * 192 + og * 16 + q * 4);
      f32x4 a;
#pragma unroll
      for (int r = 0; r < 4; ++r) a[r] = sHa[og * 16 + q * 4 + r] + (float)hb[r];
      a = __builtin_amdgcn_mfma_f32_16x16x16f16(wd, dfr[jt], a, 0, 0, 0);
      af[jt] = pack4(fmaxf(a[0], 0.f), fmaxf(a[1], 0.f), fmaxf(a[2], 0.f), fmaxf(a[3], 0.f));
    }
#pragma unroll
    for (int ft = 0; ft < 4; ++ft) {
      const f16x4 we = *(const f16x4*)&sWe2[(ft * 16 + l15) * 76 + og * 16 + q * 4];
#pragma unroll
      for (int jt = 0; jt < 4; ++jt)
        C2[ft][jt] = __builtin_amdgcn_mfma_f32_16x16x16f16(we, af[jt], C2[ft][jt], 0, 0, 0);
    }
  }
  // agg[f] = sum_j relu(C2 + be2) * mask  (rows f=16ft+4q+r, cols j)
#pragma unroll
  for (int ft = 0; ft < 4; ++ft) {
    float s[4] = {0.f, 0.f, 0.f, 0.f};
#pragma unroll
    for (int jt = 0; jt < 4; ++jt)
#pragma unroll
      for (int r = 0; r < 4; ++r)
        s[r] += fmaxf(C2[ft][jt][r] + sB[ft * 16 + q * 4 + r], 0.f) * mjt[jt];
#pragma unroll
    for (int st = 1; st < 16; st <<= 1)
#pragma unroll
      for (int r = 0; r < 4; ++r) s[r] += __shfl_xor(s[r], st, 64);
    if (l15 == 0) {
#pragma unroll
      for (int r = 0; r < 4; ++r) red[w * 64 + ft * 16 + q * 4 + r] = s[r];
    }
  }
  __syncthreads();
  if (tid < 64)
    ws[WS_AGG + node * 64 + tid] = red[tid] + red[64 + tid] + red[128 + tid] + red[192 + tid];
  __syncthreads();  // red reused below

  // ---- phase 2: category chains -> factors[c][j] --------------------------
  float fac[4][4] = {};
#pragma unroll
  for (int m = 0; m < 2; ++m) {
    float cv[4];
#pragma unroll
    for (int jt = 0; jt < 4; ++jt) {
      if (flag) {
        const u32 p = ((const u32*)cat)[node * 256 + jj[jt]];
        cv[jt] = bfld((u16)(m ? (p >> 16) : (p & 0xFFFFu)));
      } else {
        cv[jt] = ((const float*)cat)[(node * 256 + jj[jt]) * 2 + m];
      }
    }
    f32x4 C3[4];
#pragma unroll
    for (int jt = 0; jt < 4; ++jt) C3[jt] = (f32x4){0.f, 0.f, 0.f, 0.f};
#pragma unroll
    for (int og2 = 0; og2 < 4; ++og2) {
      const int og = 4 + m * 4 + og2;  // global o'-tile
      const f16x4 wd = *(const f16x4*)&sWd[(og * 16 + l15) * 20 + q * 4];
      const f16x4 wc = *(const f16x4*)&sWc2[(m * 16 + l15) * 76 + og2 * 16 + q * 4];
#pragma unroll
      for (int jt = 0; jt < 4; ++jt) {
        const f16x4 hb = *(const f16x4*)(HBJ + (b * 256 + jj[jt]) * 192 + og * 16 + q * 4);
        f32x4 a;
#pragma unroll
        for (int r = 0; r < 4; ++r) a[r] = sHa[og * 16 + q * 4 + r] + (float)hb[r];
        a = __builtin_amdgcn_mfma_f32_16x16x16f16(wd, dfr[jt], a, 0, 0, 0);
        const f16x4 af = pack4(fmaxf(a[0], 0.f), fmaxf(a[1], 0.f),
                               fmaxf(a[2], 0.f), fmaxf(a[3], 0.f));
        C3[jt] = __builtin_amdgcn_mfma_f32_16x16x16f16(wc, af, C3[jt], 0, 0, 0);
      }
    }
#pragma unroll
    for (int jt = 0; jt < 4; ++jt)
#pragma unroll
      for (int r = 0; r < 4; ++r)
        fac[jt][r] += cv[jt] * fmaxf(C3[jt][r] + sB[64 + m * 16 + q * 4 + r], 0.f);
  }

  // ---- factors MLP (f1,f2): rows c2/c3 = 4q+r, cols j ---------------------
  const f16x4 w1 = *(const f16x4*)&sWf1[l15 * 20 + q * 4];
  const f16x4 w2 = *(const f16x4*)&sWf2[l15 * 20 + q * 4];
  float ffv[4][4];
#pragma unroll
  for (int jt = 0; jt < 4; ++jt) {
    const f16x4 fF = pack4(fac[jt][0], fac[jt][1], fac[jt][2], fac[jt][3]);
    const f32x4 z = {0.f, 0.f, 0.f, 0.f};
    f32x4 G = __builtin_amdgcn_mfma_f32_16x16x16f16(w1, fF, z, 0, 0, 0);
    const f16x4 gF = pack4(fmaxf(G[0] + sB[96 + q * 4 + 0], 0.f),
                           fmaxf(G[1] + sB[96 + q * 4 + 1], 0.f),
                           fmaxf(G[2] + sB[96 + q * 4 + 2], 0.f),
                           fmaxf(G[3] + sB[96 + q * 4 + 3], 0.f));
    f32x4 F2 = __builtin_amdgcn_mfma_f32_16x16x16f16(w2, gF, z, 0, 0, 0);
#pragma unroll
    for (int r = 0; r < 4; ++r) ffv[jt][r] = fmaxf(F2[r] + sB[112 + q * 4 + r], 0.f);
  }

  // ---- coord aggregation: cacc[3c+d] = sum_j ff[c][j]*(ci-cj) -------------
  float civ[12];
#pragma unroll
  for (int r = 0; r < 4; ++r)
#pragma unroll
    for (int d = 0; d < 3; ++d) civ[r * 3 + d] = cTb[(3 * (q * 4 + r) + d) * 256 + i];
  float ca[12] = {};
#pragma unroll
  for (int jt = 0; jt < 4; ++jt)
#pragma unroll
    for (int r = 0; r < 4; ++r) {
      const float fv = ffv[jt][r];
#pragma unroll
      for (int d = 0; d < 3; ++d) {
        const float cj = cTb[(3 * (q * 4 + r) + d) * 256 + jj[jt]];
        ca[r * 3 + d] += fv * (civ[r * 3 + d] - cj);  // j==i contributes 0
      }
    }
#pragma unroll
  for (int st = 1; st < 16; st <<= 1)
#pragma unroll
    for (int u = 0; u < 12; ++u) ca[u] += __shfl_xor(ca[u], st, 64);
  if (l15 == 0) {
#pragma unroll
    for (int u = 0; u < 12; ++u) red[w * 64 + q * 12 + u] = ca[u];
  }
  __syncthreads();
  if (tid < 48)
    ws[WS_CAC + node * 48 + tid] = red[tid] + red[64 + tid] + red[128 + tid] + red[192 + tid];
}

// ---------------- K2: fused epilogue (1544 blocks x 256) --------------------
__global__ __launch_bounds__(256) void k_epilogue(const void* __restrict__ h,
                                                  const void* __restrict__ coord,
                                                  const void* __restrict__ vel,
                                                  const void* __restrict__ cat,
                                                  const void* __restrict__ Wcv,
                                                  const void* __restrict__ Wql,
                                                  const void* __restrict__ Wkl,
                                                  const float* __restrict__ ws,
                                                  void* __restrict__ outv) {
  const int blk = blockIdx.x, tid = threadIdx.x;
  const int flag = ((const int*)ws)[WS_FLAG];
  if (blk < 512) {  // node model: 4 nodes/block
    const int sub = tid >> 6, f = tid & 63;
    const int node = blk * 4 + sub;
    __shared__ float x[4][128];
    __shared__ float hid[4][64];
    const float hv = ldv(h, node * 64 + f, flag);
    x[sub][f] = hv;
    x[sub][64 + f] = ws[WS_AGG + node * 64 + f];
    __syncthreads();
    float s = ws[WS_BN1 + f];
    for (int k = 0; k < 128; ++k) s += ws[WS_WN1T + k * 64 + f] * x[sub][k];
    hid[sub][f] = fmaxf(s, 0.f);
    __syncthreads();
    float s2 = ws[WS_BN2 + f];
    for (int o = 0; o < 64; ++o) s2 += ws[WS_WN2T + o * 64 + f] * hid[sub][o];
    stv(outv, node * 64 + f, hv + s2, flag);
  } else if (blk < 520) {  // coord pipeline, b = blk-512
    const int b = blk - 512;
    const int n = tid, node = b * 256 + n;
    const int wave = n >> 6, lane = n & 63;
    __shared__ float wcv[256], wql[256], wkl[256];
    __shared__ float redm[16];
    wcv[n] = ldv(Wcv, n, flag);
    wql[n] = ldv(Wql, n, flag);
    wkl[n] = ldv(Wkl, n, flag);
    float cf[48];
#pragma unroll
    for (int cd = 0; cd < 48; ++cd) cf[cd] = ldv(coord, node * 48 + cd, flag);
    float s0 = 0.f, s1 = 0.f, s2 = 0.f;
#pragma unroll
    for (int c = 0; c < 16; ++c) { s0 += cf[c*3]; s1 += cf[c*3+1]; s2 += cf[c*3+2]; }
    for (int s = 1; s < 64; s <<= 1) {
      s0 += __shfl_xor(s0, s, 64); s1 += __shfl_xor(s1, s, 64); s2 += __shfl_xor(s2, s, 64);
    }
    if (lane == 0) { redm[wave*4] = s0; redm[wave*4+1] = s1; redm[wave*4+2] = s2; }
    __syncthreads();
    const float m0 = (redm[0]+redm[4]+redm[8]+redm[12]) * (1.f/4096.f);
    const float m1 = (redm[1]+redm[5]+redm[9]+redm[13]) * (1.f/4096.f);
    const float m2 = (redm[2]+redm[6]+redm[10]+redm[14]) * (1.f/4096.f);
    __syncthreads();
    float velf[48];
#pragma unroll
    for (int cd = 0; cd < 48; ++cd) velf[cd] = ldv(vel, node * 48 + cd, flag);
    float c3[48];
#pragma unroll
    for (int c = 0; c < 16; ++c) {
      const float at = ws[WS_ATT + node * 16 + c];
#pragma unroll
      for (int d = 0; d < 3; ++d) {
        const int cd = c * 3 + d;
        const float md = (d == 0) ? m0 : ((d == 1) ? m1 : m2);
        float cc = at * (cf[cd] - md) + cf[cd];
        cc += ws[WS_CAC + node * 48 + cd];
        float a = cc;
#pragma unroll
        for (int cp = 0; cp < 16; ++cp) a += velf[cp * 3 + d] * wcv[c * 16 + cp];
        c3[cd] = a;
      }
    }
    float t0 = 0.f, t1 = 0.f, t2 = 0.f;
#pragma unroll
    for (int c = 0; c < 16; ++c) { t0 += c3[c*3]; t1 += c3[c*3+1]; t2 += c3[c*3+2]; }
    for (int s = 1; s < 64; s <<= 1) {
      t0 += __shfl_xor(t0, s, 64); t1 += __shfl_xor(t1, s, 64); t2 += __shfl_xor(t2, s, 64);
    }
    if (lane == 0) { redm[wave*4] = t0; redm[wave*4+1] = t1; redm[wave*4+2] = t2; }
    __syncthreads();
    const float cm0 = (redm[0]+redm[4]+redm[8]+redm[12]) * (1.f/4096.f);
    const float cm1 = (redm[1]+redm[5]+redm[9]+redm[13]) * (1.f/4096.f);
    const float cm2 = (redm[2]+redm[6]+redm[10]+redm[14]) * (1.f/4096.f);
    float cc[48];
#pragma unroll
    for (int c = 0; c < 16; ++c) {
      cc[c*3]   = c3[c*3]   - cm0;
      cc[c*3+1] = c3[c*3+1] - cm1;
      cc[c*3+2] = c3[c*3+2] - cm2;
    }
#pragma unroll
    for (int o = 0; o < 16; ++o) {
      float qv[3], kv[3];
#pragma unroll
      for (int d = 0; d < 3; ++d) {
        float sq = 0.f, sk = 0.f;
#pragma unroll
        for (int cp = 0; cp < 16; ++cp) {
          sq += cc[cp * 3 + d] * wql[o * 16 + cp];
          sk += cc[cp * 3 + d] * wkl[o * 16 + cp];
        }
        qv[d] = sq; kv[d] = sk;
      }
      const float prod = qv[0]*kv[0] + qv[1]*kv[1] + qv[2]*kv[2];
      const float kns  = kv[0]*kv[0] + kv[1]*kv[1] + kv[2]*kv[2];
      const float wq = prod / (kns + EPSV);
#pragma unroll
      for (int d = 0; d < 3; ++d) {
        const float cmd = (d == 0) ? cm0 : ((d == 1) ? cm1 : cm2);
        const float val = (prod >= 0.f) ? qv[d] : (qv[d] - wq * kv[d]);
        stv(outv, 131072 + node * 48 + o * 3 + d, val + cmd, flag);
      }
    }
  } else {  // category passthrough (overwrites HA/HBJ scratch region)
    const int idx = (blk - 520) * 256 + tid;  // 262144 total
    if (flag) ((uint2*)((char*)outv + 458752))[idx] = ((const uint2*)cat)[idx];
    else      ((uint4*)((char*)outv + 917504))[idx] = ((const uint4*)cat)[idx];
  }
}

// ---------------- launch ----------------------------------------------------
extern "C" void kernel_launch(void* const* d_in, const int* in_sizes, int n_in,
                              void* d_out, int out_size, void* d_ws, size_t ws_size,
                              hipStream_t stream) {
  (void)in_sizes; (void)n_in; (void)out_size; (void)ws_size;
  const void* h    = d_in[0];
  const void* coord= d_in[1];
  const void* vel  = d_in[2];
  const void* cat  = d_in[3];
  const void* Wcv  = d_in[4];
  const void* We1  = d_in[5];
  const void* be1  = d_in[6];
  const void* We2  = d_in[7];
  const void* be2  = d_in[8];
  const void* Wc1  = d_in[9];
  const void* bc1  = d_in[10];
  const void* Wc2  = d_in[11];
  const void* bc2  = d_in[12];
  const void* Wf1  = d_in[13];
  const void* bf1v = d_in[14];
  const void* Wf2  = d_in[15];
  const void* bf2v = d_in[16];
  const void* Wn1  = d_in[17];
  const void* bn1  = d_in[18];
  const void* Wn2  = d_in[19];
  const void* bn2  = d_in[20];
  const void* Wql  = d_in[21];
  const void* Wkl  = d_in[22];
  const void* Wqm  = d_in[23];
  const void* bqm  = d_in[24];
  float* ws = (float*)d_ws;

  k_prep<<<2048, 64, 0, stream>>>(h, coord, be1, bc1, Wqm, bqm, We1, Wc1,
                                  We2, be2, Wc2, bc2, Wf1, bf1v, Wf2, bf2v,
                                  Wn1, bn1, Wn2, bn2, ws, d_out);
  k_edge<<<2048, 256, 0, stream>>>(cat, ws, d_out);
  k_epilogue<<<1544, 256, 0, stream>>>(h, coord, vel, cat, Wcv, Wql, Wkl, ws, d_out);
}

// Round 6
// 231.869 us; speedup vs baseline: 3.2051x; 1.3594x over previous
//
#include <hip/hip_runtime.h>

typedef unsigned short u16;
typedef unsigned int u32;
typedef _Float16 f16;
typedef __attribute__((ext_vector_type(2))) _Float16 f16x2;
typedef __attribute__((ext_vector_type(4))) _Float16 f16x4;
typedef __attribute__((ext_vector_type(4))) float f32x4;

// Problem constants: B=8, N=256, F=64, C=16, K=2
#define EPSV 1e-4f

// Output element offsets: h_out [0,131072) coord_out [131072,229376) category [229376,1277952)
// Category out-region is scratch: HA[2048*192] | HBJ[2048*192] | h16[2048*64] (f16)
// until the epilogue copies category in.  1.75 MB < 2 MB (bf16 case). OK.

// ---------------- ws layout (fp32 slots) -----------------------------------
static constexpr int WS_FLAG = 0;                     // +16
static constexpr int WS_ATT  = 16;                    // [2048][16]
static constexpr int WS_CT   = 32784;                 // [8][48][256] coord^T fp32
static constexpr int WS_AGG  = 131088;                // [2048][64]
static constexpr int WS_CAC  = 262160;                // [2048][48]
static constexpr int WS_WN1T = 360464;                // [128 k][64 f] fp32
static constexpr int WS_WN2T = 368656;                // [64 o][64 f] fp32
static constexpr int WS_BN1  = 372752;                // [64]
static constexpr int WS_BN2  = 372816;                // [64]
static constexpr int WS_BIAS = 372880;                // be2[64]|bc2[32]|bf1[16]|bf2[16]
static constexpr int WS_GWD  = 373008;                // f16 [192 o'][16 c]   (1536 slots)
static constexpr int WS_GWE2 = 374544;                // f16 [64 f][64 o]     (2048)
static constexpr int WS_GWC2 = 376592;                // f16 [32 mc][64 o]    (1024)
static constexpr int WS_GWF1 = 377616;                // f16 [16][16]         (128)
static constexpr int WS_GWF2 = 377744;                // f16 [16][16]         (128)
static constexpr int WS_GW1  = 377872;                // f16 [400 out][68 k]  (13600 slots)
static constexpr int WS_B400 = 391472;                // [400] layer-1 bias (0 for B-part)
// total 391872 f32 = 1.57 MB

static __device__ __forceinline__ float bfld(u16 v) {
  return __uint_as_float(((unsigned)v) << 16);
}
static __device__ __forceinline__ u16 f2b(float x) {  // RNE
  unsigned u = __float_as_uint(x);
  u += 0x7FFFu + ((u >> 16) & 1u);
  return (u16)(u >> 16);
}
static __device__ __forceinline__ float ldv(const void* p, int i, int flag) {
  return flag ? bfld(((const u16*)p)[i]) : ((const float*)p)[i];
}
static __device__ __forceinline__ void stv(void* p, int i, float v, int flag) {
  if (flag) ((u16*)p)[i] = f2b(v);
  else      ((float*)p)[i] = v;
}
static __device__ __forceinline__ f16* scratchHA(void* outv, int flag) {
  return (f16*)((char*)outv + (size_t)229376 * (flag ? 2 : 4));
}
static __device__ __forceinline__ int sniff_flag(const void* h) {
  const u16* hu = (const u16*)h;
  int cnt = 0;
  for (int i = 0; i < 128; ++i) {
    unsigned e = (hu[i] >> 7) & 0xFFu;
    if ((e >= 100u && e <= 150u) || hu[i] == 0) ++cnt;
  }
  return (cnt >= 112) ? 1 : 0;
}
static __device__ __forceinline__ f16x4 pack4(float a, float b, float c, float d) {
  const f16x2 lo = __builtin_bit_cast(f16x2, __builtin_amdgcn_cvt_pkrtz(a, b));
  const f16x2 hi = __builtin_bit_cast(f16x2, __builtin_amdgcn_cvt_pkrtz(c, d));
  f16x4 r; r[0] = lo[0]; r[1] = lo[1]; r[2] = hi[0]; r[3] = hi[1]; return r;
}

// ---------------- K0: all table builds, fully parallel (64 x 256) -----------
__global__ __launch_bounds__(256) void k_prep_w(
    const void* __restrict__ h, const void* __restrict__ coord,
    const void* __restrict__ We1, const void* __restrict__ Wc1,
    const void* __restrict__ We2, const void* __restrict__ Wc2,
    const void* __restrict__ Wf1, const void* __restrict__ Wf2,
    const void* __restrict__ Wn1, const void* __restrict__ Wn2,
    const void* __restrict__ Wqm,
    const void* __restrict__ be1, const void* __restrict__ bc1,
    const void* __restrict__ bqm, const void* __restrict__ be2,
    const void* __restrict__ bc2, const void* __restrict__ bf1,
    const void* __restrict__ bf2, const void* __restrict__ bn1,
    const void* __restrict__ bn2,
    float* __restrict__ ws, void* __restrict__ outv) {
  const int t = blockIdx.x * 256 + threadIdx.x;
  const int STR = 16384;
  __shared__ int sflag;
  if (threadIdx.x == 0) {
    sflag = sniff_flag(h);
    if (blockIdx.x == 0) ((int*)ws)[WS_FLAG] = sflag;
  }
  __syncthreads();
  const int flag = sflag;

  // GW1: stacked layer-1 weights as [400 out][68 k] f16
  //   out 0..191: cols 0..63 (h_i part, We1|Wc1); 192..383: cols 64..127; 384..399: Wqm
  f16* gw1 = (f16*)(ws + WS_GW1);
  for (int idx = t; idx < 25600; idx += STR) {
    const int row = idx >> 6, k = idx & 63;
    float v;
    if (row < 64)       v = ldv(We1, row * 144 + k, flag);
    else if (row < 192) v = ldv(Wc1, (row - 64) * 144 + k, flag);
    else if (row < 384) {
      const int ro = row - 192;
      v = (ro < 64) ? ldv(We1, ro * 144 + 64 + k, flag)
                    : ldv(Wc1, (ro - 64) * 144 + 64 + k, flag);
    } else              v = ldv(Wqm, (row - 384) * 64 + k, flag);
    gw1[row * 68 + k] = (f16)v;
  }
  if (t < 400) {
    float v = (t < 64) ? ldv(be1, t, flag)
            : (t < 192) ? ldv(bc1, t - 64, flag)
            : (t < 384) ? 0.f : ldv(bqm, t - 384, flag);
    ws[WS_B400 + t] = v;
  }
  // h16 into out-scratch
  f16* h16 = scratchHA(outv, flag) + 2048 * 384;
  for (int idx = t; idx < 131072; idx += STR) h16[idx] = (f16)ldv(h, idx, flag);
  // coord^T [b][cd][n] fp32 (dest-linear)
  for (int idx = t; idx < 98304; idx += STR) {
    const int bq = idx / 12288, rem = idx - bq * 12288;
    const int cd = rem >> 8, n = rem & 255;
    ws[WS_CT + idx] = ldv(coord, (bq * 256 + n) * 48 + cd, flag);
  }
  // k_edge tables
  f16* gwd  = (f16*)(ws + WS_GWD);
  f16* gwe2 = (f16*)(ws + WS_GWE2);
  f16* gwc2 = (f16*)(ws + WS_GWC2);
  f16* gwf1 = (f16*)(ws + WS_GWF1);
  f16* gwf2 = (f16*)(ws + WS_GWF2);
  for (int idx = t; idx < 3072; idx += STR) {  // [o'][c] <- cols 128..143
    const int o = idx >> 4, c = idx & 15;
    const void* src = (o < 64) ? We1 : Wc1;
    const int row = (o < 64) ? o : (o - 64);
    gwd[idx] = (f16)ldv(src, row * 144 + 128 + c, flag);
  }
  for (int idx = t; idx < 4096; idx += STR) gwe2[idx] = (f16)ldv(We2, idx, flag);
  for (int idx = t; idx < 2048; idx += STR) gwc2[idx] = (f16)ldv(Wc2, idx, flag);
  if (t < 256) { gwf1[t] = (f16)ldv(Wf1, t, flag); gwf2[t] = (f16)ldv(Wf2, t, flag); }
  // node-model tables
  for (int idx = t; idx < 8192; idx += STR) {  // Wn1T[k][f]
    const int k = idx >> 6, f = idx & 63;
    ws[WS_WN1T + idx] = ldv(Wn1, f * 128 + k, flag);
  }
  for (int idx = t; idx < 4096; idx += STR) {  // Wn2T[o][f]
    const int o = idx >> 6, f = idx & 63;
    ws[WS_WN2T + idx] = ldv(Wn2, f * 64 + o, flag);
  }
  if (t < 64)  ws[WS_BN1 + t] = ldv(bn1, t, flag);
  if (t >= 64 && t < 128) ws[WS_BN2 + t - 64] = ldv(bn2, t - 64, flag);
  if (t >= 128 && t < 192) ws[WS_BIAS + t - 128] = ldv(be2, t - 128, flag);
  if (t >= 192 && t < 224) ws[WS_BIAS + 64 + t - 192] = ldv(bc2, t - 192, flag);
  if (t >= 224 && t < 240) ws[WS_BIAS + 96 + t - 224] = ldv(bf1, t - 224, flag);
  if (t >= 240 && t < 256) ws[WS_BIAS + 112 + t - 240] = ldv(bf2, t - 240, flag);
}

// ---------------- K0b: layer-1 MFMA GEMM -> HA/HBJ/ATT (160 x 256) ----------
// C[node][out] = h16[node][k] . GW1[out][k] + bias400[out]; M=2048,N=400,K=64.
// 32 node-tiles x 5 out-groups(80). Wave = 16 nodes; A from global h16,
// B from LDS; D: m=node(q*4+r), n=out(l15).
__global__ __launch_bounds__(256) void k_gemm(float* __restrict__ ws,
                                              void* __restrict__ outv) {
  const int flag = ((const int*)ws)[WS_FLAG];
  const int nt = blockIdx.x / 5, grp = blockIdx.x % 5;
  const int tid = threadIdx.x, w = tid >> 6, lane = tid & 63;
  const int q = lane >> 4, l15 = lane & 15;
  f16* HA16 = scratchHA(outv, flag);
  f16* HBJ  = HA16 + 2048 * 192;
  const f16* h16 = HA16 + 2048 * 384;
  __shared__ __align__(16) f16 sW[80 * 68];
  __shared__ float sBias[80];
  const u32* gw1 = (const u32*)(ws + WS_GW1);
  for (int idx = tid; idx < 2720; idx += 256) {
    const int r = idx / 34, c = idx - r * 34;
    *(u32*)&sW[r * 68 + c * 2] = gw1[(grp * 80 + r) * 34 + c];
  }
  if (tid < 80) sBias[tid] = ws[WS_B400 + grp * 80 + tid];
  __syncthreads();
  const int nodeA = nt * 64 + w * 16 + l15;
  f16x4 Af[4];
#pragma unroll
  for (int ks = 0; ks < 4; ++ks)
    Af[ks] = *(const f16x4*)(h16 + nodeA * 64 + ks * 16 + q * 4);
#pragma unroll
  for (int ot = 0; ot < 5; ++ot) {
    const float bv = sBias[ot * 16 + l15];
    f32x4 acc = (f32x4){bv, bv, bv, bv};
#pragma unroll
    for (int ks = 0; ks < 4; ++ks) {
      const f16x4 Bf = *(const f16x4*)&sW[(ot * 16 + l15) * 68 + ks * 16 + q * 4];
      acc = __builtin_amdgcn_mfma_f32_16x16x16f16(Af[ks], Bf, acc, 0, 0, 0);
    }
    const int out = grp * 80 + ot * 16 + l15;
    const int nodeD = nt * 64 + w * 16 + q * 4;
#pragma unroll
    for (int r = 0; r < 4; ++r) {
      const int node = nodeD + r;
      if (out < 192)      HA16[node * 192 + out] = (f16)acc[r];
      else if (out < 384) HBJ[node * 192 + out - 192] = (f16)acc[r];
      else                ws[WS_ATT + node * 16 + out - 384] = fmaxf(acc[r], 0.f);
    }
  }
}

// ---------------- K1: MFMA edge kernel (2048 blocks x 256) ------------------
__global__ __launch_bounds__(256, 4) void k_edge(const void* __restrict__ cat,
                                                 float* __restrict__ ws,
                                                 void* __restrict__ outv) {
  const int node = blockIdx.x, b = node >> 8, i = node & 255;
  const int tid = threadIdx.x;
  const int w = tid >> 6, lane = tid & 63, q = lane >> 4, l15 = lane & 15;
  const int flag = ((const int*)ws)[WS_FLAG];
  const f16* HA16 = scratchHA(outv, flag);
  const f16* HBJ  = HA16 + 2048 * 192;
  const float* __restrict__ cTb = ws + WS_CT + b * 48 * 256;

  __shared__ __align__(16) f16 sWd[192 * 20];
  __shared__ __align__(16) f16 sWe2[64 * 76];
  __shared__ __align__(16) f16 sWc2[32 * 76];
  __shared__ __align__(16) f16 sWf1[16 * 20];
  __shared__ __align__(16) f16 sWf2[16 * 20];
  __shared__ __align__(16) f16 distS[256 * 20];
  __shared__ float sHa[192];
  __shared__ float sB[128];
  __shared__ __align__(16) float red[256];

  {  // stage weight tables
    const u32* gwd = (const u32*)(ws + WS_GWD);
    for (int idx = tid; idx < 1536; idx += 256) {
      const int r = idx >> 3, c = idx & 7;
      *(u32*)&sWd[r * 20 + c * 2] = gwd[idx];
    }
    const u32* gwe = (const u32*)(ws + WS_GWE2);
    for (int idx = tid; idx < 2048; idx += 256) {
      const int r = idx >> 5, c = idx & 31;
      *(u32*)&sWe2[r * 76 + c * 2] = gwe[idx];
    }
    const u32* gwc = (const u32*)(ws + WS_GWC2);
    for (int idx = tid; idx < 1024; idx += 256) {
      const int r = idx >> 5, c = idx & 31;
      *(u32*)&sWc2[r * 76 + c * 2] = gwc[idx];
    }
    if (tid < 128) {
      const int r = tid >> 3, c = tid & 7;
      *(u32*)&sWf1[r * 20 + c * 2] = ((const u32*)(ws + WS_GWF1))[tid];
      *(u32*)&sWf2[r * 20 + c * 2] = ((const u32*)(ws + WS_GWF2))[tid];
    }
    if (tid < 192) sHa[tid] = (float)HA16[node * 192 + tid];
    if (tid < 128) sB[tid] = ws[WS_BIAS + tid];
  }
  {  // distances
    float dr[16];
#pragma unroll
    for (int c = 0; c < 16; ++c) {
      float s = 0.f;
#pragma unroll
      for (int d = 0; d < 3; ++d) {
        const int cd = c * 3 + d;
        const float df = cTb[cd * 256 + i] - cTb[cd * 256 + tid];
        s += df * df;
      }
      dr[c] = sqrtf(s);
    }
#pragma unroll
    for (int kk = 0; kk < 4; ++kk)
      *(f16x4*)&distS[tid * 20 + kk * 4] =
          pack4(dr[4 * kk], dr[4 * kk + 1], dr[4 * kk + 2], dr[4 * kk + 3]);
  }
  __syncthreads();

  int jj[4]; float mjt[4]; f16x4 dfr[4];
#pragma unroll
  for (int jt = 0; jt < 4; ++jt) {
    jj[jt] = w * 64 + jt * 16 + l15;
    mjt[jt] = (jj[jt] == i) ? 0.f : 1.f;
    dfr[jt] = *(const f16x4*)&distS[jj[jt] * 20 + q * 4];
  }

  // ---- phase 1: e2 GEMM chain ----
  f32x4 C2[4][4];
#pragma unroll
  for (int ft = 0; ft < 4; ++ft)
#pragma unroll
    for (int jt = 0; jt < 4; ++jt) C2[ft][jt] = (f32x4){0.f, 0.f, 0.f, 0.f};
#pragma unroll
  for (int og = 0; og < 4; ++og) {
    const f16x4 wd = *(const f16x4*)&sWd[(og * 16 + l15) * 20 + q * 4];
    f16x4 af[4];
#pragma unroll
    for (int jt = 0; jt < 4; ++jt) {
      const f16x4 hb = *(const f16x4*)(HBJ + (b * 256 + jj[jt]) * 192 + og * 16 + q * 4);
      f32x4 a;
#pragma unroll
      for (int r = 0; r < 4; ++r) a[r] = sHa[og * 16 + q * 4 + r] + (float)hb[r];
      a = __builtin_amdgcn_mfma_f32_16x16x16f16(wd, dfr[jt], a, 0, 0, 0);
      af[jt] = pack4(fmaxf(a[0], 0.f), fmaxf(a[1], 0.f), fmaxf(a[2], 0.f), fmaxf(a[3], 0.f));
    }
#pragma unroll
    for (int ft = 0; ft < 4; ++ft) {
      const f16x4 we = *(const f16x4*)&sWe2[(ft * 16 + l15) * 76 + og * 16 + q * 4];
#pragma unroll
      for (int jt = 0; jt < 4; ++jt)
        C2[ft][jt] = __builtin_amdgcn_mfma_f32_16x16x16f16(we, af[jt], C2[ft][jt], 0, 0, 0);
    }
  }
#pragma unroll
  for (int ft = 0; ft < 4; ++ft) {
    float s[4] = {0.f, 0.f, 0.f, 0.f};
#pragma unroll
    for (int jt = 0; jt < 4; ++jt)
#pragma unroll
      for (int r = 0; r < 4; ++r)
        s[r] += fmaxf(C2[ft][jt][r] + sB[ft * 16 + q * 4 + r], 0.f) * mjt[jt];
#pragma unroll
    for (int st = 1; st < 16; st <<= 1)
#pragma unroll
      for (int r = 0; r < 4; ++r) s[r] += __shfl_xor(s[r], st, 64);
    if (l15 == 0) {
#pragma unroll
      for (int r = 0; r < 4; ++r) red[w * 64 + ft * 16 + q * 4 + r] = s[r];
    }
  }
  __syncthreads();
  if (tid < 64)
    ws[WS_AGG + node * 64 + tid] = red[tid] + red[64 + tid] + red[128 + tid] + red[192 + tid];
  __syncthreads();

  // ---- phase 2: category chains -> factors ----
  float fac[4][4] = {};
#pragma unroll
  for (int m = 0; m < 2; ++m) {
    float cv[4];
#pragma unroll
    for (int jt = 0; jt < 4; ++jt) {
      if (flag) {
        const u32 p = ((const u32*)cat)[node * 256 + jj[jt]];
        cv[jt] = bfld((u16)(m ? (p >> 16) : (p & 0xFFFFu)));
      } else {
        cv[jt] = ((const float*)cat)[(node * 256 + jj[jt]) * 2 + m];
      }
    }
    f32x4 C3[4];
#pragma unroll
    for (int jt = 0; jt < 4; ++jt) C3[jt] = (f32x4){0.f, 0.f, 0.f, 0.f};
#pragma unroll
    for (int og2 = 0; og2 < 4; ++og2) {
      const int og = 4 + m * 4 + og2;
      const f16x4 wd = *(const f16x4*)&sWd[(og * 16 + l15) * 20 + q * 4];
      const f16x4 wc = *(const f16x4*)&sWc2[(m * 16 + l15) * 76 + og2 * 16 + q * 4];
#pragma unroll
      for (int jt = 0; jt < 4; ++jt) {
        const f16x4 hb = *(const f16x4*)(HBJ + (b * 256 + jj[jt]) * 192 + og * 16 + q * 4);
        f32x4 a;
#pragma unroll
        for (int r = 0; r < 4; ++r) a[r] = sHa[og * 16 + q * 4 + r] + (float)hb[r];
        a = __builtin_amdgcn_mfma_f32_16x16x16f16(wd, dfr[jt], a, 0, 0, 0);
        const f16x4 af = pack4(fmaxf(a[0], 0.f), fmaxf(a[1], 0.f),
                               fmaxf(a[2], 0.f), fmaxf(a[3], 0.f));
        C3[jt] = __builtin_amdgcn_mfma_f32_16x16x16f16(wc, af, C3[jt], 0, 0, 0);
      }
    }
#pragma unroll
    for (int jt = 0; jt < 4; ++jt)
#pragma unroll
      for (int r = 0; r < 4; ++r)
        fac[jt][r] += cv[jt] * fmaxf(C3[jt][r] + sB[64 + m * 16 + q * 4 + r], 0.f);
  }

  // ---- factors MLP ----
  const f16x4 w1 = *(const f16x4*)&sWf1[l15 * 20 + q * 4];
  const f16x4 w2 = *(const f16x4*)&sWf2[l15 * 20 + q * 4];
  float ffv[4][4];
#pragma unroll
  for (int jt = 0; jt < 4; ++jt) {
    const f16x4 fF = pack4(fac[jt][0], fac[jt][1], fac[jt][2], fac[jt][3]);
    const f32x4 z = {0.f, 0.f, 0.f, 0.f};
    f32x4 G = __builtin_amdgcn_mfma_f32_16x16x16f16(w1, fF, z, 0, 0, 0);
    const f16x4 gF = pack4(fmaxf(G[0] + sB[96 + q * 4 + 0], 0.f),
                           fmaxf(G[1] + sB[96 + q * 4 + 1], 0.f),
                           fmaxf(G[2] + sB[96 + q * 4 + 2], 0.f),
                           fmaxf(G[3] + sB[96 + q * 4 + 3], 0.f));
    f32x4 F2 = __builtin_amdgcn_mfma_f32_16x16x16f16(w2, gF, z, 0, 0, 0);
#pragma unroll
    for (int r = 0; r < 4; ++r) ffv[jt][r] = fmaxf(F2[r] + sB[112 + q * 4 + r], 0.f);
  }

  // ---- coord aggregation ----
  float civ[12];
#pragma unroll
  for (int r = 0; r < 4; ++r)
#pragma unroll
    for (int d = 0; d < 3; ++d) civ[r * 3 + d] = cTb[(3 * (q * 4 + r) + d) * 256 + i];
  float ca[12] = {};
#pragma unroll
  for (int jt = 0; jt < 4; ++jt)
#pragma unroll
    for (int r = 0; r < 4; ++r) {
      const float fv = ffv[jt][r];
#pragma unroll
      for (int d = 0; d < 3; ++d) {
        const float cj = cTb[(3 * (q * 4 + r) + d) * 256 + jj[jt]];
        ca[r * 3 + d] += fv * (civ[r * 3 + d] - cj);
      }
    }
#pragma unroll
  for (int st = 1; st < 16; st <<= 1)
#pragma unroll
    for (int u = 0; u < 12; ++u) ca[u] += __shfl_xor(ca[u], st, 64);
  if (l15 == 0) {
#pragma unroll
    for (int u = 0; u < 12; ++u) red[w * 64 + q * 12 + u] = ca[u];
  }
  __syncthreads();
  if (tid < 48)
    ws[WS_CAC + node * 48 + tid] = red[tid] + red[64 + tid] + red[128 + tid] + red[192 + tid];
}

// ---------------- K2: fused epilogue (1096 blocks x 256) --------------------
__global__ __launch_bounds__(256) void k_epilogue(const void* __restrict__ h,
                                                  const void* __restrict__ coord,
                                                  const void* __restrict__ vel,
                                                  const void* __restrict__ cat,
                                                  const void* __restrict__ Wcv,
                                                  const void* __restrict__ Wql,
                                                  const void* __restrict__ Wkl,
                                                  const float* __restrict__ ws,
                                                  void* __restrict__ outv) {
  const int blk = blockIdx.x, tid = threadIdx.x;
  const int flag = ((const int*)ws)[WS_FLAG];
  if (blk < 64) {  // node model: 32 nodes/block, LDS-staged weights
    const int sub = tid >> 6, f = tid & 63;
    __shared__ float sWn1[128 * 64];
    __shared__ float sWn2[64 * 64];
    __shared__ float sbn[128];
    __shared__ float x[4][128];
    __shared__ float hid[4][64];
    for (int idx = tid; idx < 8192; idx += 256) sWn1[idx] = ws[WS_WN1T + idx];
    for (int idx = tid; idx < 4096; idx += 256) sWn2[idx] = ws[WS_WN2T + idx];
    if (tid < 64) sbn[tid] = ws[WS_BN1 + tid];
    else if (tid < 128) sbn[tid] = ws[WS_BN2 + tid - 64];
    __syncthreads();
    for (int c = 0; c < 8; ++c) {
      const int node = blk * 32 + c * 4 + sub;
      const float hv = ldv(h, node * 64 + f, flag);
      x[sub][f] = hv;                             // wave-internal LDS, no barrier
      x[sub][64 + f] = ws[WS_AGG + node * 64 + f];
      float s = sbn[f];
      for (int k = 0; k < 128; ++k) s += sWn1[k * 64 + f] * x[sub][k];
      hid[sub][f] = fmaxf(s, 0.f);
      float s2 = sbn[64 + f];
      for (int o = 0; o < 64; ++o) s2 += sWn2[o * 64 + f] * hid[sub][o];
      stv(outv, node * 64 + f, hv + s2, flag);
    }
  } else if (blk < 72) {  // coord pipeline, b = blk-64
    const int b = blk - 64;
    const int n = tid, node = b * 256 + n;
    const int wave = n >> 6, lane = n & 63;
    __shared__ float wcv[256], wql[256], wkl[256];
    __shared__ float redm[16];
    wcv[n] = ldv(Wcv, n, flag);
    wql[n] = ldv(Wql, n, flag);
    wkl[n] = ldv(Wkl, n, flag);
    float cf[48];
#pragma unroll
    for (int cd = 0; cd < 48; ++cd) cf[cd] = ldv(coord, node * 48 + cd, flag);
    float s0 = 0.f, s1 = 0.f, s2 = 0.f;
#pragma unroll
    for (int c = 0; c < 16; ++c) { s0 += cf[c*3]; s1 += cf[c*3+1]; s2 += cf[c*3+2]; }
    for (int s = 1; s < 64; s <<= 1) {
      s0 += __shfl_xor(s0, s, 64); s1 += __shfl_xor(s1, s, 64); s2 += __shfl_xor(s2, s, 64);
    }
    if (lane == 0) { redm[wave*4] = s0; redm[wave*4+1] = s1; redm[wave*4+2] = s2; }
    __syncthreads();
    const float m0 = (redm[0]+redm[4]+redm[8]+redm[12]) * (1.f/4096.f);
    const float m1 = (redm[1]+redm[5]+redm[9]+redm[13]) * (1.f/4096.f);
    const float m2 = (redm[2]+redm[6]+redm[10]+redm[14]) * (1.f/4096.f);
    __syncthreads();
    float velf[48];
#pragma unroll
    for (int cd = 0; cd < 48; ++cd) velf[cd] = ldv(vel, node * 48 + cd, flag);
    float c3[48];
#pragma unroll
    for (int c = 0; c < 16; ++c) {
      const float at = ws[WS_ATT + node * 16 + c];
#pragma unroll
      for (int d = 0; d < 3; ++d) {
        const int cd = c * 3 + d;
        const float md = (d == 0) ? m0 : ((d == 1) ? m1 : m2);
        float cc = at * (cf[cd] - md) + cf[cd];
        cc += ws[WS_CAC + node * 48 + cd];
        float a = cc;
#pragma unroll
        for (int cp = 0; cp < 16; ++cp) a += velf[cp * 3 + d] * wcv[c * 16 + cp];
        c3[cd] = a;
      }
    }
    float t0 = 0.f, t1 = 0.f, t2 = 0.f;
#pragma unroll
    for (int c = 0; c < 16; ++c) { t0 += c3[c*3]; t1 += c3[c*3+1]; t2 += c3[c*3+2]; }
    for (int s = 1; s < 64; s <<= 1) {
      t0 += __shfl_xor(t0, s, 64); t1 += __shfl_xor(t1, s, 64); t2 += __shfl_xor(t2, s, 64);
    }
    if (lane == 0) { redm[wave*4] = t0; redm[wave*4+1] = t1; redm[wave*4+2] = t2; }
    __syncthreads();
    const float cm0 = (redm[0]+redm[4]+redm[8]+redm[12]) * (1.f/4096.f);
    const float cm1 = (redm[1]+redm[5]+redm[9]+redm[13]) * (1.f/4096.f);
    const float cm2 = (redm[2]+redm[6]+redm[10]+redm[14]) * (1.f/4096.f);
    float cc[48];
#pragma unroll
    for (int c = 0; c < 16; ++c) {
      cc[c*3]   = c3[c*3]   - cm0;
      cc[c*3+1] = c3[c*3+1] - cm1;
      cc[c*3+2] = c3[c*3+2] - cm2;
    }
#pragma unroll
    for (int o = 0; o < 16; ++o) {
      float qv[3], kv[3];
#pragma unroll
      for (int d = 0; d < 3; ++d) {
        float sq = 0.f, sk = 0.f;
#pragma unroll
        for (int cp = 0; cp < 16; ++cp) {
          sq += cc[cp * 3 + d] * wql[o * 16 + cp];
          sk += cc[cp * 3 + d] * wkl[o * 16 + cp];
        }
        qv[d] = sq; kv[d] = sk;
      }
      const float prod = qv[0]*kv[0] + qv[1]*kv[1] + qv[2]*kv[2];
      const float kns  = kv[0]*kv[0] + kv[1]*kv[1] + kv[2]*kv[2];
      const float wq = prod / (kns + EPSV);
#pragma unroll
      for (int d = 0; d < 3; ++d) {
        const float cmd = (d == 0) ? cm0 : ((d == 1) ? cm1 : cm2);
        const float val = (prod >= 0.f) ? qv[d] : (qv[d] - wq * kv[d]);
        stv(outv, 131072 + node * 48 + o * 3 + d, val + cmd, flag);
      }
    }
  } else {  // category passthrough (overwrites scratch region)
    const int idx = (blk - 72) * 256 + tid;  // 262144 total
    if (flag) ((uint2*)((char*)outv + 458752))[idx] = ((const uint2*)cat)[idx];
    else      ((uint4*)((char*)outv + 917504))[idx] = ((const uint4*)cat)[idx];
  }
}

// ---------------- launch ----------------------------------------------------
extern "C" void kernel_launch(void* const* d_in, const int* in_sizes, int n_in,
                              void* d_out, int out_size, void* d_ws, size_t ws_size,
                              hipStream_t stream) {
  (void)in_sizes; (void)n_in; (void)out_size; (void)ws_size;
  const void* h    = d_in[0];
  const void* coord= d_in[1];
  const void* vel  = d_in[2];
  const void* cat  = d_in[3];
  const void* Wcv  = d_in[4];
  const void* We1  = d_in[5];
  const void* be1  = d_in[6];
  const void* We2  = d_in[7];
  const void* be2  = d_in[8];
  const void* Wc1  = d_in[9];
  const void* bc1  = d_in[10];
  const void* Wc2  = d_in[11];
  const void* bc2  = d_in[12];
  const void* Wf1  = d_in[13];
  const void* bf1v = d_in[14];
  const void* Wf2  = d_in[15];
  const void* bf2v = d_in[16];
  const void* Wn1  = d_in[17];
  const void* bn1  = d_in[18];
  const void* Wn2  = d_in[19];
  const void* bn2  = d_in[20];
  const void* Wql  = d_in[21];
  const void* Wkl  = d_in[22];
  const void* Wqm  = d_in[23];
  const void* bqm  = d_in[24];
  float* ws = (float*)d_ws;

  k_prep_w<<<64, 256, 0, stream>>>(h, coord, We1, Wc1, We2, Wc2, Wf1, Wf2,
                                   Wn1, Wn2, Wqm, be1, bc1, bqm, be2, bc2,
                                   bf1v, bf2v, bn1, bn2, ws, d_out);
  k_gemm<<<160, 256, 0, stream>>>(ws, d_out);
  k_edge<<<2048, 256, 0, stream>>>(cat, ws, d_out);
  k_epilogue<<<1096, 256, 0, stream>>>(h, coord, vel, cat, Wcv, Wql, Wkl, ws, d_out);
}